// Round 1
// baseline (1341.890 us; speedup 1.0000x reference)
//
#include <hip/hip_runtime.h>
#include <cstdint>
#include <cstddef>

// Problem constants
#define Bsz   2
#define Sseq  1024
#define Ddim  2048
#define Hq    32
#define Hkv   8
#define HDm   64
#define MROWS (Bsz * Sseq)   // 2048
#define NQc   (Hq * HDm)     // 2048
#define NKVc  (Hkv * HDm)    // 512

// ---------------------------------------------------------------------------
// Tiled fp32 GEMM: C[M,N] = A[M,K] @ B[K,N]; tile 128x128x16, 256 thr, 8x8/thr
// (fp32 => vector ALU only on CDNA4; this is the baseline to beat with MFMA)
// ---------------------------------------------------------------------------
__global__ __launch_bounds__(256)
void gemm_f32(const float* __restrict__ A, const float* __restrict__ Bm,
              float* __restrict__ C, int Ndim, int Kdim)
{
    __shared__ float As[16][132];   // transposed A tile, padded (write conflicts ~2-way)
    __shared__ float Bs[16][128];
    const int t    = threadIdx.x;
    const int row0 = blockIdx.y * 128;
    const int col0 = blockIdx.x * 128;
    const int tx   = t & 15, ty = t >> 4;

    float acc[8][8] = {};

    for (int k0 = 0; k0 < Kdim; k0 += 16) {
#pragma unroll
        for (int c = 0; c < 2; ++c) {
            const int f  = t + c * 256;
            // A: 128 rows x 16 cols, store transposed As[k][m]
            const int ar = f >> 2;
            const int ac = (f & 3) << 2;
            const float4 va = *reinterpret_cast<const float4*>(
                A + (size_t)(row0 + ar) * Kdim + k0 + ac);
            As[ac + 0][ar] = va.x;
            As[ac + 1][ar] = va.y;
            As[ac + 2][ar] = va.z;
            As[ac + 3][ar] = va.w;
            // B: 16 rows x 128 cols, row-major
            const int br = f >> 5;
            const int bc = (f & 31) << 2;
            *reinterpret_cast<float4*>(&Bs[br][bc]) =
                *reinterpret_cast<const float4*>(
                    Bm + (size_t)(k0 + br) * Ndim + col0 + bc);
        }
        __syncthreads();

#pragma unroll
        for (int kk = 0; kk < 16; ++kk) {
            float a[8], b[8];
            *reinterpret_cast<float4*>(&a[0]) =
                *reinterpret_cast<const float4*>(&As[kk][ty * 8]);
            *reinterpret_cast<float4*>(&a[4]) =
                *reinterpret_cast<const float4*>(&As[kk][ty * 8 + 4]);
            *reinterpret_cast<float4*>(&b[0]) =
                *reinterpret_cast<const float4*>(&Bs[kk][tx * 8]);
            *reinterpret_cast<float4*>(&b[4]) =
                *reinterpret_cast<const float4*>(&Bs[kk][tx * 8 + 4]);
#pragma unroll
            for (int i = 0; i < 8; ++i)
#pragma unroll
                for (int j = 0; j < 8; ++j)
                    acc[i][j] = fmaf(a[i], b[j], acc[i][j]);
        }
        __syncthreads();
    }

#pragma unroll
    for (int i = 0; i < 8; ++i) {
        float* cp = C + (size_t)(row0 + ty * 8 + i) * Ndim + col0 + tx * 8;
#pragma unroll
        for (int j = 0; j < 8; j += 4) {
            *reinterpret_cast<float4*>(cp + j) =
                make_float4(acc[i][j], acc[i][j + 1], acc[i][j + 2], acc[i][j + 3]);
        }
    }
}

// ---------------------------------------------------------------------------
// RoPE (in-place on q and k buffers). cos/sin indexed by LOCAL seq position
// (matches reference: tables built for arange(S)). Memory-bound, ~10us.
// ---------------------------------------------------------------------------
__global__ __launch_bounds__(256)
void rope_kernel(float* __restrict__ qbuf, float* __restrict__ kbuf,
                 const float* __restrict__ cosT, const float* __restrict__ sinT)
{
    const int idx  = blockIdx.x * 256 + threadIdx.x;  // MROWS * 40 heads * 32 pairs
    const int p    = idx & 31;          // pair index d in [0,32)
    const int tmp  = idx >> 5;
    const int head = tmp % (Hq + Hkv);  // 0..31 q-heads, 32..39 k-heads
    const int row  = tmp / (Hq + Hkv);  // 0..2047
    const int s    = row & (Sseq - 1);

    const float c  = cosT[s * HDm + p];
    const float sn = sinT[s * HDm + p];

    float* base = (head < Hq)
        ? (qbuf + (size_t)row * NQc + head * HDm)
        : (kbuf + (size_t)row * NKVc + (head - Hq) * HDm);

    const float t1 = base[p];
    const float t2 = base[p + 32];
    base[p]      = t1 * c - t2 * sn;   // out[d]     = t[d]*cos - t[d+32]*sin
    base[p + 32] = t2 * c + t1 * sn;   // out[d+32]  = t[d+32]*cos + t[d]*sin
}

// ---------------------------------------------------------------------------
// Flash attention fp32, causal, GQA (4 q-heads per kv-head).
// Block = (qblock of 64 rows) x head x batch; 256 threads, 4x4 per thread.
// K stored transposed in LDS (conflict-free b128 col reads); P reuses K^T LDS.
// ---------------------------------------------------------------------------
__global__ __launch_bounds__(256)
void flash_attn(const float* __restrict__ Qb, const float* __restrict__ Kb,
                const float* __restrict__ Vb, float* __restrict__ Ob,
                const int* __restrict__ spp)
{
    __shared__ float Qs[64][68];
    __shared__ float KtPs[64][68];   // K^T during QK^T, then P during PV
    __shared__ float Vs[64][68];

    const int qb = blockIdx.x;       // 16 q-blocks
    const int h  = blockIdx.y;       // 32 q-heads
    const int b  = blockIdx.z;       // 2 batches
    const int g  = h >> 2;           // kv head
    const int sp = *spp;             // start_pos (0 in practice)
    const int t  = threadIdx.x;
    const int tx = t & 15, ty = t >> 4;

    // Load Q tile, pre-scaled by 1/sqrt(64)
#pragma unroll
    for (int c = 0; c < 4; ++c) {
        const int f  = t + c * 256;
        const int r  = f >> 4;
        const int cc = (f & 15) << 2;
        float4 v = *reinterpret_cast<const float4*>(
            Qb + (size_t)(b * Sseq + qb * 64 + r) * NQc + h * HDm + cc);
        v.x *= 0.125f; v.y *= 0.125f; v.z *= 0.125f; v.w *= 0.125f;
        *reinterpret_cast<float4*>(&Qs[r][cc]) = v;
    }

    float m_i[4], l_i[4], Ov[4][4];
#pragma unroll
    for (int i = 0; i < 4; ++i) {
        m_i[i] = -1e30f;
        l_i[i] = 0.f;
#pragma unroll
        for (int j = 0; j < 4; ++j) Ov[i][j] = 0.f;
    }

    const int qmax = qb * 64 + 63 + sp;
    const int nkb  = min(Sseq / 64, qmax / 64 + 1);

    for (int kb = 0; kb < nkb; ++kb) {
        __syncthreads();   // prev iter's PV reads of KtPs/Vs complete
        // Load K (transposed) and V tiles
#pragma unroll
        for (int c = 0; c < 4; ++c) {
            const int f  = t + c * 256;
            const int r  = f >> 4;
            const int cc = (f & 15) << 2;
            const size_t goff = (size_t)(b * Sseq + kb * 64 + r) * NKVc + g * HDm + cc;
            const float4 kv4 = *reinterpret_cast<const float4*>(Kb + goff);
            KtPs[cc + 0][r] = kv4.x;
            KtPs[cc + 1][r] = kv4.y;
            KtPs[cc + 2][r] = kv4.z;
            KtPs[cc + 3][r] = kv4.w;
            *reinterpret_cast<float4*>(&Vs[r][cc]) =
                *reinterpret_cast<const float4*>(Vb + goff);
        }
        __syncthreads();

        // S = Q K^T  (scores for rows ty*4.., cols tx*4..)
        float sc[4][4] = {};
#pragma unroll
        for (int d4 = 0; d4 < 16; ++d4) {
            float qa[4][4], kk4[4][4];
#pragma unroll
            for (int i = 0; i < 4; ++i)
                *reinterpret_cast<float4*>(qa[i]) =
                    *reinterpret_cast<const float4*>(&Qs[ty * 4 + i][d4 * 4]);
#pragma unroll
            for (int dd = 0; dd < 4; ++dd)
                *reinterpret_cast<float4*>(kk4[dd]) =
                    *reinterpret_cast<const float4*>(&KtPs[d4 * 4 + dd][tx * 4]);
#pragma unroll
            for (int i = 0; i < 4; ++i)
#pragma unroll
                for (int dd = 0; dd < 4; ++dd)
#pragma unroll
                    for (int j = 0; j < 4; ++j)
                        sc[i][j] = fmaf(qa[i][dd], kk4[dd][j], sc[i][j]);
        }
        __syncthreads();   // everyone done reading K^T before P overwrites it

        // Causal mask (only needed at/past the diagonal tile)
        if (kb * 64 + 63 > qb * 64 + sp) {
#pragma unroll
            for (int i = 0; i < 4; ++i)
#pragma unroll
                for (int j = 0; j < 4; ++j)
                    if (kb * 64 + tx * 4 + j > qb * 64 + ty * 4 + i + sp)
                        sc[i][j] = -1e30f;
        }

        // Online softmax per q-row (row group = 16 lanes sharing ty)
#pragma unroll
        for (int i = 0; i < 4; ++i) {
            float mx = fmaxf(fmaxf(sc[i][0], sc[i][1]), fmaxf(sc[i][2], sc[i][3]));
#pragma unroll
            for (int msk = 1; msk < 16; msk <<= 1)
                mx = fmaxf(mx, __shfl_xor(mx, msk, 16));
            const float m_new = fmaxf(m_i[i], mx);
            const float corr  = __expf(m_i[i] - m_new);
            m_i[i] = m_new;
            float rs = 0.f;
#pragma unroll
            for (int j = 0; j < 4; ++j) {
                const float p = __expf(sc[i][j] - m_new);
                sc[i][j] = p;
                rs += p;
            }
#pragma unroll
            for (int msk = 1; msk < 16; msk <<= 1)
                rs += __shfl_xor(rs, msk, 16);
            l_i[i] = l_i[i] * corr + rs;
#pragma unroll
            for (int j = 0; j < 4; ++j) Ov[i][j] *= corr;
            *reinterpret_cast<float4*>(&KtPs[ty * 4 + i][tx * 4]) =
                make_float4(sc[i][0], sc[i][1], sc[i][2], sc[i][3]);
        }
        __syncthreads();   // P tile visible

        // O += P @ V
#pragma unroll
        for (int j4 = 0; j4 < 16; ++j4) {
            float pa[4][4], vv[4][4];
#pragma unroll
            for (int i = 0; i < 4; ++i)
                *reinterpret_cast<float4*>(pa[i]) =
                    *reinterpret_cast<const float4*>(&KtPs[ty * 4 + i][j4 * 4]);
#pragma unroll
            for (int jj = 0; jj < 4; ++jj)
                *reinterpret_cast<float4*>(vv[jj]) =
                    *reinterpret_cast<const float4*>(&Vs[j4 * 4 + jj][tx * 4]);
#pragma unroll
            for (int i = 0; i < 4; ++i)
#pragma unroll
                for (int jj = 0; jj < 4; ++jj)
#pragma unroll
                    for (int cc2 = 0; cc2 < 4; ++cc2)
                        Ov[i][cc2] = fmaf(pa[i][jj], vv[jj][cc2], Ov[i][cc2]);
        }
    }

    // Normalize and store attention output [row][h*64 + col]
#pragma unroll
    for (int i = 0; i < 4; ++i) {
        const float inv = 1.0f / l_i[i];
        *reinterpret_cast<float4*>(
            Ob + (size_t)(b * Sseq + qb * 64 + ty * 4 + i) * NQc + h * HDm + tx * 4) =
            make_float4(Ov[i][0] * inv, Ov[i][1] * inv, Ov[i][2] * inv, Ov[i][3] * inv);
    }
}

// ---------------------------------------------------------------------------
// Launcher
// ---------------------------------------------------------------------------
extern "C" void kernel_launch(void* const* d_in, const int* in_sizes, int n_in,
                              void* d_out, int out_size, void* d_ws, size_t ws_size,
                              hipStream_t stream)
{
    const float* x    = (const float*)d_in[0];
    const float* wq   = (const float*)d_in[1];
    const float* wk   = (const float*)d_in[2];
    const float* wv   = (const float*)d_in[3];
    const float* wo   = (const float*)d_in[4];
    const float* cosT = (const float*)d_in[5];
    const float* sinT = (const float*)d_in[6];
    const int*   spp  = (const int*)d_in[7];
    float*       out  = (float*)d_out;

    // Workspace layout (floats): q[2048*2048] k[2048*512] v[2048*512] ao[2048*2048]
    float* qbuf = (float*)d_ws;
    float* kbuf = qbuf + (size_t)MROWS * NQc;
    float* vbuf = kbuf + (size_t)MROWS * NKVc;
    float* ao   = vbuf + (size_t)MROWS * NKVc;

    // QKV projections
    gemm_f32<<<dim3(NQc  / 128, MROWS / 128), 256, 0, stream>>>(x, wq, qbuf, NQc,  Ddim);
    gemm_f32<<<dim3(NKVc / 128, MROWS / 128), 256, 0, stream>>>(x, wk, kbuf, NKVc, Ddim);
    gemm_f32<<<dim3(NKVc / 128, MROWS / 128), 256, 0, stream>>>(x, wv, vbuf, NKVc, Ddim);

    // RoPE on q and k (in place)
    rope_kernel<<<(MROWS * (Hq + Hkv) * 32) / 256, 256, 0, stream>>>(qbuf, kbuf, cosT, sinT);

    // Causal GQA flash attention
    flash_attn<<<dim3(Sseq / 64, Hq, Bsz), 256, 0, stream>>>(qbuf, kbuf, vbuf, ao, spp);

    // Output projection
    gemm_f32<<<dim3(Ddim / 128, MROWS / 128), 256, 0, stream>>>(ao, wo, out, Ddim, NQc);
}

// Round 2
// 712.849 us; speedup vs baseline: 1.8824x; 1.8824x over previous
//
#include <hip/hip_runtime.h>
#include <cstdint>
#include <cstddef>

// Problem constants
#define Bsz   2
#define Sseq  1024
#define Ddim  2048
#define Hq    32
#define Hkv   8
#define HDm   64
#define MROWS (Bsz * Sseq)   // 2048
#define NQc   (Hq * HDm)     // 2048
#define NKVc  (Hkv * HDm)    // 512

typedef __attribute__((ext_vector_type(8))) short bf16x8;
typedef __attribute__((ext_vector_type(4))) float f32x4;

// bf16 round-to-nearest-even helpers
__device__ __forceinline__ ushort f2bf(float x) {
    uint32_t u = __float_as_uint(x);
    uint32_t r = (u + 0x7FFFu + ((u >> 16) & 1u)) >> 16;
    return (ushort)r;
}
__device__ __forceinline__ float bf2f(ushort h) {
    return __uint_as_float(((uint32_t)h) << 16);
}

// async global->LDS, 16B per lane; LDS dest is wave-uniform base + lane*16
__device__ __forceinline__ void gload_lds16(const void* g, void* s) {
    __builtin_amdgcn_global_load_lds(
        (const __attribute__((address_space(1))) void*)g,
        (__attribute__((address_space(3))) void*)s, 16, 0, 0);
}

// ---------------------------------------------------------------------------
// fp32 -> bf16 hi/lo split, same layout. One thread per 8 floats.
// ---------------------------------------------------------------------------
__global__ __launch_bounds__(256)
void conv_split(const float* __restrict__ in, ushort* __restrict__ hi,
                ushort* __restrict__ lo)
{
    const int i = blockIdx.x * 256 + threadIdx.x;
    const float4 v0 = reinterpret_cast<const float4*>(in)[i * 2];
    const float4 v1 = reinterpret_cast<const float4*>(in)[i * 2 + 1];
    const float a[8] = {v0.x, v0.y, v0.z, v0.w, v1.x, v1.y, v1.z, v1.w};
    union { ushort u16[8]; uint4 v; } ph, pl;
#pragma unroll
    for (int j = 0; j < 8; ++j) {
        const ushort h = f2bf(a[j]);
        ph.u16[j] = h;
        pl.u16[j] = f2bf(a[j] - bf2f(h));
    }
    reinterpret_cast<uint4*>(hi)[i] = ph.v;
    reinterpret_cast<uint4*>(lo)[i] = pl.v;
}

// ---------------------------------------------------------------------------
// fp32 [R][C] -> transposed bf16 hi/lo [C][R]. 32x32 LDS tile transpose.
// ---------------------------------------------------------------------------
__global__ __launch_bounds__(256)
void conv_split_t(const float* __restrict__ in, ushort* __restrict__ hi,
                  ushort* __restrict__ lo, int R, int C)
{
    __shared__ float tile[32][33];
    const int r0 = blockIdx.y * 32, c0 = blockIdx.x * 32;
    const int tx = threadIdx.x & 31, ty = threadIdx.x >> 5;  // 32 x 8
#pragma unroll
    for (int p = 0; p < 4; ++p) {
        const int r = ty + p * 8;
        tile[r][tx] = in[(size_t)(r0 + r) * C + c0 + tx];
    }
    __syncthreads();
#pragma unroll
    for (int p = 0; p < 4; ++p) {
        const int cc = ty + p * 8;           // local col -> output row
        const float a = tile[tx][cc];        // conflict-free (stride 33)
        const ushort h = f2bf(a);
        hi[(size_t)(c0 + cc) * R + r0 + tx] = h;
        lo[(size_t)(c0 + cc) * R + r0 + tx] = f2bf(a - bf2f(h));
    }
}

// ---------------------------------------------------------------------------
// Split-bf16 MFMA GEMM: C[M][N](f32) = (Ahi+Alo) @ (Bhi+Blo)^T
//   A   : bf16 [M][K] row-major (hi, lo)
//   Bt  : bf16 [N][K] row-major (hi, lo)  ("gemm_bt" layout: A/B frags identical)
//   C = Ahi*Bhi + Ahi*Blo + Alo*Bhi   (lo*lo dropped, ~2^-18 relative)
// Tile 128x128, BK=32, 4 waves (2x2), each wave 64x64 = 4x4 frags of 16x16x32.
// m97-style 2-barrier loop, global_load_lds width 16, linear LDS.
// ---------------------------------------------------------------------------
__global__ __launch_bounds__(256)
void gemm_split(const ushort* __restrict__ Ahi, const ushort* __restrict__ Alo,
                const ushort* __restrict__ Bthi, const ushort* __restrict__ Btlo,
                float* __restrict__ C, int ldc, int Kdim)
{
    __shared__ ushort sAhi[128 * 32];
    __shared__ ushort sAlo[128 * 32];
    __shared__ ushort sBhi[128 * 32];
    __shared__ ushort sBlo[128 * 32];

    const int t    = threadIdx.x;
    const int lane = t & 63;
    const int wid  = t >> 6;            // 0..3
    const int wr   = wid >> 1;          // wave row (0..1) -> 64 rows
    const int wc   = wid & 1;           // wave col (0..1) -> 64 cols
    const int row0 = blockIdx.y * 128;
    const int col0 = blockIdx.x * 128;

    f32x4 acc[4][4];
#pragma unroll
    for (int m = 0; m < 4; ++m)
#pragma unroll
        for (int n = 0; n < 4; ++n)
            acc[m][n] = (f32x4){0.f, 0.f, 0.f, 0.f};

    const int fr = lane & 15;           // fragment row/col within 16
    const int kc = (lane >> 4) * 8;     // k-chunk start (8 bf16)

    for (int k0 = 0; k0 < Kdim; k0 += 32) {
        __syncthreads();   // previous iteration done reading LDS

        // Stage 4 tiles of [128][32] bf16 (8KB each): per wave 2 calls/tile.
        // LDS layout linear row-major; call (wid*2+c) covers rows (wid*2+c)*16..+15.
#pragma unroll
        for (int c = 0; c < 2; ++c) {
            const int rr = (wid * 2 + c) * 16 + (lane >> 2);
            const int cb = (lane & 3) * 8;
            const size_t ga = (size_t)(row0 + rr) * Kdim + k0 + cb;
            const size_t gb = (size_t)(col0 + rr) * Kdim + k0 + cb;
            char* const dst = (char*)nullptr;
            (void)dst;
            gload_lds16(Ahi  + ga, (char*)sAhi + (wid * 2 + c) * 1024);
            gload_lds16(Alo  + ga, (char*)sAlo + (wid * 2 + c) * 1024);
            gload_lds16(Bthi + gb, (char*)sBhi + (wid * 2 + c) * 1024);
            gload_lds16(Btlo + gb, (char*)sBlo + (wid * 2 + c) * 1024);
        }
        __syncthreads();   // vmcnt(0) drained before barrier -> tiles visible

        bf16x8 ah[4], al[4], bh[4], bl[4];
        const int ar = wr * 64 + fr;
        const int br = wc * 64 + fr;
#pragma unroll
        for (int m = 0; m < 4; ++m) {
            ah[m] = *reinterpret_cast<const bf16x8*>(&sAhi[(ar + m * 16) * 32 + kc]);
            al[m] = *reinterpret_cast<const bf16x8*>(&sAlo[(ar + m * 16) * 32 + kc]);
        }
#pragma unroll
        for (int n = 0; n < 4; ++n) {
            bh[n] = *reinterpret_cast<const bf16x8*>(&sBhi[(br + n * 16) * 32 + kc]);
            bl[n] = *reinterpret_cast<const bf16x8*>(&sBlo[(br + n * 16) * 32 + kc]);
        }
#pragma unroll
        for (int m = 0; m < 4; ++m)
#pragma unroll
            for (int n = 0; n < 4; ++n) {
                acc[m][n] = __builtin_amdgcn_mfma_f32_16x16x32_bf16(ah[m], bh[n], acc[m][n], 0, 0, 0);
                acc[m][n] = __builtin_amdgcn_mfma_f32_16x16x32_bf16(ah[m], bl[n], acc[m][n], 0, 0, 0);
                acc[m][n] = __builtin_amdgcn_mfma_f32_16x16x32_bf16(al[m], bh[n], acc[m][n], 0, 0, 0);
            }
    }

    // Epilogue: C/D layout col=lane&15, row=(lane>>4)*4+reg  [verified m89/m91]
    const int fq = lane >> 4;
#pragma unroll
    for (int m = 0; m < 4; ++m)
#pragma unroll
        for (int j = 0; j < 4; ++j) {
            float* cp = C + (size_t)(row0 + wr * 64 + m * 16 + fq * 4 + j) * ldc
                          + col0 + wc * 64 + fr;
#pragma unroll
            for (int n = 0; n < 4; ++n) cp[n * 16] = acc[m][n][j];
        }
}

// ---------------------------------------------------------------------------
// RoPE (in-place on q and k buffers), fp32, memory-bound.
// ---------------------------------------------------------------------------
__global__ __launch_bounds__(256)
void rope_kernel(float* __restrict__ qbuf, float* __restrict__ kbuf,
                 const float* __restrict__ cosT, const float* __restrict__ sinT)
{
    const int idx  = blockIdx.x * 256 + threadIdx.x;
    const int p    = idx & 31;
    const int tmp  = idx >> 5;
    const int head = tmp % (Hq + Hkv);
    const int row  = tmp / (Hq + Hkv);
    const int s    = row & (Sseq - 1);

    const float c  = cosT[s * HDm + p];
    const float sn = sinT[s * HDm + p];

    float* base = (head < Hq)
        ? (qbuf + (size_t)row * NQc + head * HDm)
        : (kbuf + (size_t)row * NKVc + (head - Hq) * HDm);

    const float t1 = base[p];
    const float t2 = base[p + 32];
    base[p]      = t1 * c - t2 * sn;
    base[p + 32] = t2 * c + t1 * sn;
}

// ---------------------------------------------------------------------------
// Flash attention fp32, causal, GQA (unchanged from round 1 — known-good).
// ---------------------------------------------------------------------------
__global__ __launch_bounds__(256)
void flash_attn(const float* __restrict__ Qb, const float* __restrict__ Kb,
                const float* __restrict__ Vb, float* __restrict__ Ob,
                const int* __restrict__ spp)
{
    __shared__ float Qs[64][68];
    __shared__ float KtPs[64][68];
    __shared__ float Vs[64][68];

    const int qb = blockIdx.x;
    const int h  = blockIdx.y;
    const int b  = blockIdx.z;
    const int g  = h >> 2;
    const int sp = *spp;
    const int t  = threadIdx.x;
    const int tx = t & 15, ty = t >> 4;

#pragma unroll
    for (int c = 0; c < 4; ++c) {
        const int f  = t + c * 256;
        const int r  = f >> 4;
        const int cc = (f & 15) << 2;
        float4 v = *reinterpret_cast<const float4*>(
            Qb + (size_t)(b * Sseq + qb * 64 + r) * NQc + h * HDm + cc);
        v.x *= 0.125f; v.y *= 0.125f; v.z *= 0.125f; v.w *= 0.125f;
        *reinterpret_cast<float4*>(&Qs[r][cc]) = v;
    }

    float m_i[4], l_i[4], Ov[4][4];
#pragma unroll
    for (int i = 0; i < 4; ++i) {
        m_i[i] = -1e30f;
        l_i[i] = 0.f;
#pragma unroll
        for (int j = 0; j < 4; ++j) Ov[i][j] = 0.f;
    }

    const int qmax = qb * 64 + 63 + sp;
    const int nkb  = min(Sseq / 64, qmax / 64 + 1);

    for (int kb = 0; kb < nkb; ++kb) {
        __syncthreads();
#pragma unroll
        for (int c = 0; c < 4; ++c) {
            const int f  = t + c * 256;
            const int r  = f >> 4;
            const int cc = (f & 15) << 2;
            const size_t goff = (size_t)(b * Sseq + kb * 64 + r) * NKVc + g * HDm + cc;
            const float4 kv4 = *reinterpret_cast<const float4*>(Kb + goff);
            KtPs[cc + 0][r] = kv4.x;
            KtPs[cc + 1][r] = kv4.y;
            KtPs[cc + 2][r] = kv4.z;
            KtPs[cc + 3][r] = kv4.w;
            *reinterpret_cast<float4*>(&Vs[r][cc]) =
                *reinterpret_cast<const float4*>(Vb + goff);
        }
        __syncthreads();

        float sc[4][4] = {};
#pragma unroll
        for (int d4 = 0; d4 < 16; ++d4) {
            float qa[4][4], kk4[4][4];
#pragma unroll
            for (int i = 0; i < 4; ++i)
                *reinterpret_cast<float4*>(qa[i]) =
                    *reinterpret_cast<const float4*>(&Qs[ty * 4 + i][d4 * 4]);
#pragma unroll
            for (int dd = 0; dd < 4; ++dd)
                *reinterpret_cast<float4*>(kk4[dd]) =
                    *reinterpret_cast<const float4*>(&KtPs[d4 * 4 + dd][tx * 4]);
#pragma unroll
            for (int i = 0; i < 4; ++i)
#pragma unroll
                for (int dd = 0; dd < 4; ++dd)
#pragma unroll
                    for (int j = 0; j < 4; ++j)
                        sc[i][j] = fmaf(qa[i][dd], kk4[dd][j], sc[i][j]);
        }
        __syncthreads();

        if (kb * 64 + 63 > qb * 64 + sp) {
#pragma unroll
            for (int i = 0; i < 4; ++i)
#pragma unroll
                for (int j = 0; j < 4; ++j)
                    if (kb * 64 + tx * 4 + j > qb * 64 + ty * 4 + i + sp)
                        sc[i][j] = -1e30f;
        }

#pragma unroll
        for (int i = 0; i < 4; ++i) {
            float mx = fmaxf(fmaxf(sc[i][0], sc[i][1]), fmaxf(sc[i][2], sc[i][3]));
#pragma unroll
            for (int msk = 1; msk < 16; msk <<= 1)
                mx = fmaxf(mx, __shfl_xor(mx, msk, 16));
            const float m_new = fmaxf(m_i[i], mx);
            const float corr  = __expf(m_i[i] - m_new);
            m_i[i] = m_new;
            float rs = 0.f;
#pragma unroll
            for (int j = 0; j < 4; ++j) {
                const float p = __expf(sc[i][j] - m_new);
                sc[i][j] = p;
                rs += p;
            }
#pragma unroll
            for (int msk = 1; msk < 16; msk <<= 1)
                rs += __shfl_xor(rs, msk, 16);
            l_i[i] = l_i[i] * corr + rs;
#pragma unroll
            for (int j = 0; j < 4; ++j) Ov[i][j] *= corr;
            *reinterpret_cast<float4*>(&KtPs[ty * 4 + i][tx * 4]) =
                make_float4(sc[i][0], sc[i][1], sc[i][2], sc[i][3]);
        }
        __syncthreads();

#pragma unroll
        for (int j4 = 0; j4 < 16; ++j4) {
            float pa[4][4], vv[4][4];
#pragma unroll
            for (int i = 0; i < 4; ++i)
                *reinterpret_cast<float4*>(pa[i]) =
                    *reinterpret_cast<const float4*>(&KtPs[ty * 4 + i][j4 * 4]);
#pragma unroll
            for (int jj = 0; jj < 4; ++jj)
                *reinterpret_cast<float4*>(vv[jj]) =
                    *reinterpret_cast<const float4*>(&Vs[j4 * 4 + jj][tx * 4]);
#pragma unroll
            for (int i = 0; i < 4; ++i)
#pragma unroll
                for (int jj = 0; jj < 4; ++jj)
#pragma unroll
                    for (int cc2 = 0; cc2 < 4; ++cc2)
                        Ov[i][cc2] = fmaf(pa[i][jj], vv[jj][cc2], Ov[i][cc2]);
        }
    }

#pragma unroll
    for (int i = 0; i < 4; ++i) {
        const float inv = 1.0f / l_i[i];
        *reinterpret_cast<float4*>(
            Ob + (size_t)(b * Sseq + qb * 64 + ty * 4 + i) * NQc + h * HDm + tx * 4) =
            make_float4(Ov[i][0] * inv, Ov[i][1] * inv, Ov[i][2] * inv, Ov[i][3] * inv);
    }
}

// ---------------------------------------------------------------------------
// Launcher. Workspace layout (80 MB total), with aliasing:
//   [ 0..16) wqT hi/lo   [16..24) wkT hi/lo  [24..32)... see below
// ---------------------------------------------------------------------------
extern "C" void kernel_launch(void* const* d_in, const int* in_sizes, int n_in,
                              void* d_out, int out_size, void* d_ws, size_t ws_size,
                              hipStream_t stream)
{
    const float* x    = (const float*)d_in[0];
    const float* wq   = (const float*)d_in[1];
    const float* wk   = (const float*)d_in[2];
    const float* wv   = (const float*)d_in[3];
    const float* wo   = (const float*)d_in[4];
    const float* cosT = (const float*)d_in[5];
    const float* sinT = (const float*)d_in[6];
    const int*   spp  = (const int*)d_in[7];
    float*       out  = (float*)d_out;

    char* w = (char*)d_ws;
    ushort* wqThi = (ushort*)(w);                        // [2048][2048] 8MB
    ushort* wqTlo = (ushort*)(w + (8ull  << 20));
    ushort* wkThi = (ushort*)(w + (16ull << 20));        // [512][2048] 2MB
    ushort* wkTlo = (ushort*)(w + (18ull << 20));
    ushort* wvThi = (ushort*)(w + (20ull << 20));
    ushort* wvTlo = (ushort*)(w + (22ull << 20));
    ushort* woThi = (ushort*)(w + (24ull << 20));        // [2048][2048] 8MB
    ushort* woTlo = (ushort*)(w + (32ull << 20));
    ushort* xhi   = (ushort*)(w + (40ull << 20));        // 8MB
    ushort* xlo   = (ushort*)(w + (48ull << 20));        // 8MB
    float*  ao    = (float*) (w + (40ull << 20));        // 16MB, aliases xhi/xlo (dead by then)
    float*  qbuf  = (float*) (w + (56ull << 20));        // 16MB
    ushort* aohi  = (ushort*)(w + (56ull << 20));        // aliases qbuf (dead by then)
    ushort* aolo  = (ushort*)(w + (64ull << 20));
    float*  kbuf  = (float*) (w + (72ull << 20));        // 4MB
    float*  vbuf  = (float*) (w + (76ull << 20));        // 4MB  -> 80MB total

    // hi/lo conversions
    conv_split<<<2048, 256, 0, stream>>>(x, xhi, xlo);
    conv_split_t<<<dim3(64, 64), 256, 0, stream>>>(wq, wqThi, wqTlo, Ddim, NQc);
    conv_split_t<<<dim3(16, 64), 256, 0, stream>>>(wk, wkThi, wkTlo, Ddim, NKVc);
    conv_split_t<<<dim3(16, 64), 256, 0, stream>>>(wv, wvThi, wvTlo, Ddim, NKVc);
    conv_split_t<<<dim3(64, 64), 256, 0, stream>>>(wo, woThi, woTlo, NQc, Ddim);

    // QKV projections (split-bf16 MFMA, fp32-grade)
    gemm_split<<<dim3(16, 16), 256, 0, stream>>>(xhi, xlo, wqThi, wqTlo, qbuf, NQc,  Ddim);
    gemm_split<<<dim3(4,  16), 256, 0, stream>>>(xhi, xlo, wkThi, wkTlo, kbuf, NKVc, Ddim);
    gemm_split<<<dim3(4,  16), 256, 0, stream>>>(xhi, xlo, wvThi, wvTlo, vbuf, NKVc, Ddim);

    // RoPE (fp32, in place)
    rope_kernel<<<(MROWS * (Hq + Hkv) * 32) / 256, 256, 0, stream>>>(qbuf, kbuf, cosT, sinT);

    // Causal GQA flash attention (fp32)
    flash_attn<<<dim3(Sseq / 64, Hq, Bsz), 256, 0, stream>>>(qbuf, kbuf, vbuf, ao, spp);

    // Output projection
    conv_split<<<2048, 256, 0, stream>>>(ao, aohi, aolo);
    gemm_split<<<dim3(16, 16), 256, 0, stream>>>(aohi, aolo, woThi, woTlo, out, Ddim, NQc);
}

// Round 4
// 367.033 us; speedup vs baseline: 3.6560x; 1.9422x over previous
//
#include <hip/hip_runtime.h>
#include <cstdint>
#include <cstddef>

// Problem constants
#define Bsz   2
#define Sseq  1024
#define Ddim  2048
#define Hq    32
#define Hkv   8
#define HDm   64
#define MROWS (Bsz * Sseq)   // 2048
#define NQc   (Hq * HDm)     // 2048
#define NKVc  (Hkv * HDm)    // 512

typedef __attribute__((ext_vector_type(8))) short    bf16x8;
typedef __attribute__((ext_vector_type(8))) _Float16 f16x8;
typedef __attribute__((ext_vector_type(4))) float    f32x4;

// bf16 round-to-nearest-even helpers
__device__ __forceinline__ ushort f2bf(float x) {
    uint32_t u = __float_as_uint(x);
    uint32_t r = (u + 0x7FFFu + ((u >> 16) & 1u)) >> 16;
    return (ushort)r;
}
__device__ __forceinline__ float bf2f(ushort h) {
    return __uint_as_float(((uint32_t)h) << 16);
}

// async global->LDS, 16B per lane; LDS dest is wave-uniform base + lane*16
__device__ __forceinline__ void gload_lds16(const void* g, void* s) {
    __builtin_amdgcn_global_load_lds(
        (const __attribute__((address_space(1))) void*)g,
        (__attribute__((address_space(3))) void*)s, 16, 0, 0);
}

// ---------------------------------------------------------------------------
// fp32 -> bf16 hi/lo split, same layout. One thread per 8 floats.
// ---------------------------------------------------------------------------
__global__ __launch_bounds__(256)
void conv_split(const float* __restrict__ in, ushort* __restrict__ hi,
                ushort* __restrict__ lo)
{
    const int i = blockIdx.x * 256 + threadIdx.x;
    const float4 v0 = reinterpret_cast<const float4*>(in)[i * 2];
    const float4 v1 = reinterpret_cast<const float4*>(in)[i * 2 + 1];
    const float a[8] = {v0.x, v0.y, v0.z, v0.w, v1.x, v1.y, v1.z, v1.w};
    union { ushort u16[8]; uint4 v; } ph, pl;
#pragma unroll
    for (int j = 0; j < 8; ++j) {
        const ushort h = f2bf(a[j]);
        ph.u16[j] = h;
        pl.u16[j] = f2bf(a[j] - bf2f(h));
    }
    reinterpret_cast<uint4*>(hi)[i] = ph.v;
    reinterpret_cast<uint4*>(lo)[i] = pl.v;
}

// ---------------------------------------------------------------------------
// fp32 [R][C] -> transposed bf16 hi/lo [C][R]. 32x32 LDS tile transpose.
// ---------------------------------------------------------------------------
__global__ __launch_bounds__(256)
void conv_split_t(const float* __restrict__ in, ushort* __restrict__ hi,
                  ushort* __restrict__ lo, int R, int C)
{
    __shared__ float tile[32][33];
    const int r0 = blockIdx.y * 32, c0 = blockIdx.x * 32;
    const int tx = threadIdx.x & 31, ty = threadIdx.x >> 5;  // 32 x 8
#pragma unroll
    for (int p = 0; p < 4; ++p) {
        const int r = ty + p * 8;
        tile[r][tx] = in[(size_t)(r0 + r) * C + c0 + tx];
    }
    __syncthreads();
#pragma unroll
    for (int p = 0; p < 4; ++p) {
        const int cc = ty + p * 8;
        const float a = tile[tx][cc];
        const ushort h = f2bf(a);
        hi[(size_t)(c0 + cc) * R + r0 + tx] = h;
        lo[(size_t)(c0 + cc) * R + r0 + tx] = f2bf(a - bf2f(h));
    }
}

// ---------------------------------------------------------------------------
// Split-bf16 MFMA GEMM core (128x128 tile, BK=32, 4 waves).
// C = Ahi*Bhi + Ahi*Blo + Alo*Bhi  (fp32-grade)
// ---------------------------------------------------------------------------
__device__ __forceinline__
void gemm_split_body(const ushort* __restrict__ Ahi, const ushort* __restrict__ Alo,
                     const ushort* __restrict__ Bthi, const ushort* __restrict__ Btlo,
                     float* __restrict__ C, int ldc, int Kdim,
                     int row0, int col0,
                     ushort* sAhi, ushort* sAlo, ushort* sBhi, ushort* sBlo)
{
    const int t    = threadIdx.x;
    const int lane = t & 63;
    const int wid  = t >> 6;
    const int wr   = wid >> 1;
    const int wc   = wid & 1;

    f32x4 acc[4][4];
#pragma unroll
    for (int m = 0; m < 4; ++m)
#pragma unroll
        for (int n = 0; n < 4; ++n)
            acc[m][n] = (f32x4){0.f, 0.f, 0.f, 0.f};

    const int fr = lane & 15;
    const int kc = (lane >> 4) * 8;

    for (int k0 = 0; k0 < Kdim; k0 += 32) {
        __syncthreads();
#pragma unroll
        for (int c = 0; c < 2; ++c) {
            const int rr = (wid * 2 + c) * 16 + (lane >> 2);
            const int cb = (lane & 3) * 8;
            const size_t ga = (size_t)(row0 + rr) * Kdim + k0 + cb;
            const size_t gb = (size_t)(col0 + rr) * Kdim + k0 + cb;
            gload_lds16(Ahi  + ga, (char*)sAhi + (wid * 2 + c) * 1024);
            gload_lds16(Alo  + ga, (char*)sAlo + (wid * 2 + c) * 1024);
            gload_lds16(Bthi + gb, (char*)sBhi + (wid * 2 + c) * 1024);
            gload_lds16(Btlo + gb, (char*)sBlo + (wid * 2 + c) * 1024);
        }
        __syncthreads();

        bf16x8 ah[4], al[4], bh[4], bl[4];
        const int ar = wr * 64 + fr;
        const int br = wc * 64 + fr;
#pragma unroll
        for (int m = 0; m < 4; ++m) {
            ah[m] = *reinterpret_cast<const bf16x8*>(&sAhi[(ar + m * 16) * 32 + kc]);
            al[m] = *reinterpret_cast<const bf16x8*>(&sAlo[(ar + m * 16) * 32 + kc]);
        }
#pragma unroll
        for (int n = 0; n < 4; ++n) {
            bh[n] = *reinterpret_cast<const bf16x8*>(&sBhi[(br + n * 16) * 32 + kc]);
            bl[n] = *reinterpret_cast<const bf16x8*>(&sBlo[(br + n * 16) * 32 + kc]);
        }
#pragma unroll
        for (int m = 0; m < 4; ++m)
#pragma unroll
            for (int n = 0; n < 4; ++n) {
                acc[m][n] = __builtin_amdgcn_mfma_f32_16x16x32_bf16(ah[m], bh[n], acc[m][n], 0, 0, 0);
                acc[m][n] = __builtin_amdgcn_mfma_f32_16x16x32_bf16(ah[m], bl[n], acc[m][n], 0, 0, 0);
                acc[m][n] = __builtin_amdgcn_mfma_f32_16x16x32_bf16(al[m], bh[n], acc[m][n], 0, 0, 0);
            }
    }

    const int fq = lane >> 4;
#pragma unroll
    for (int m = 0; m < 4; ++m)
#pragma unroll
        for (int j = 0; j < 4; ++j) {
            float* cp = C + (size_t)(row0 + wr * 64 + m * 16 + fq * 4 + j) * ldc
                          + col0 + wc * 64 + fr;
#pragma unroll
            for (int n = 0; n < 4; ++n) cp[n * 16] = acc[m][n][j];
        }
}

// Out-projection GEMM (single B/C)
__global__ __launch_bounds__(256)
void gemm_split(const ushort* __restrict__ Ahi, const ushort* __restrict__ Alo,
                const ushort* __restrict__ Bthi, const ushort* __restrict__ Btlo,
                float* __restrict__ C, int ldc, int Kdim)
{
    __shared__ ushort sAhi[128 * 32];
    __shared__ ushort sAlo[128 * 32];
    __shared__ ushort sBhi[128 * 32];
    __shared__ ushort sBlo[128 * 32];
    gemm_split_body(Ahi, Alo, Bthi, Btlo, C, ldc, Kdim,
                    blockIdx.y * 128, blockIdx.x * 128,
                    sAhi, sAlo, sBhi, sBlo);
}

// Fused QKV projection: one dispatch, grid.x = 16(q)+4(k)+4(v) = 24 col-tiles
__global__ __launch_bounds__(256)
void gemm_qkv(const ushort* __restrict__ Ahi, const ushort* __restrict__ Alo,
              const ushort* __restrict__ Bqh, const ushort* __restrict__ Bql,
              const ushort* __restrict__ Bkh, const ushort* __restrict__ Bkl,
              const ushort* __restrict__ Bvh, const ushort* __restrict__ Bvl,
              float* __restrict__ Cq, float* __restrict__ Ck, float* __restrict__ Cv)
{
    __shared__ ushort sAhi[128 * 32];
    __shared__ ushort sAlo[128 * 32];
    __shared__ ushort sBhi[128 * 32];
    __shared__ ushort sBlo[128 * 32];
    const int bx = blockIdx.x;
    const ushort* Bthi; const ushort* Btlo; float* C; int ldc, col0;
    if (bx < 16)      { Bthi = Bqh; Btlo = Bql; C = Cq; ldc = NQc;  col0 = bx * 128; }
    else if (bx < 20) { Bthi = Bkh; Btlo = Bkl; C = Ck; ldc = NKVc; col0 = (bx - 16) * 128; }
    else              { Bthi = Bvh; Btlo = Bvl; C = Cv; ldc = NKVc; col0 = (bx - 20) * 128; }
    gemm_split_body(Ahi, Alo, Bthi, Btlo, C, ldc, Ddim,
                    blockIdx.y * 128, col0, sAhi, sAlo, sBhi, sBlo);
}

// ---------------------------------------------------------------------------
// RoPE (in-place on q and k fp32 buffers).
// ---------------------------------------------------------------------------
__global__ __launch_bounds__(256)
void rope_kernel(float* __restrict__ qbuf, float* __restrict__ kbuf,
                 const float* __restrict__ cosT, const float* __restrict__ sinT)
{
    const int idx  = blockIdx.x * 256 + threadIdx.x;
    const int p    = idx & 31;
    const int tmp  = idx >> 5;
    const int head = tmp % (Hq + Hkv);
    const int row  = tmp / (Hq + Hkv);
    const int s    = row & (Sseq - 1);

    const float c  = cosT[s * HDm + p];
    const float sn = sinT[s * HDm + p];

    float* base = (head < Hq)
        ? (qbuf + (size_t)row * NQc + head * HDm)
        : (kbuf + (size_t)row * NKVc + (head - Hq) * HDm);

    const float t1 = base[p];
    const float t2 = base[p + 32];
    base[p]      = t1 * c - t2 * sn;
    base[p + 32] = t2 * c + t1 * sn;
}

// ---------------------------------------------------------------------------
// Pack kbuf fp32 -> fp16 (same layout). 8 elems/thread.
// ---------------------------------------------------------------------------
__global__ __launch_bounds__(256)
void pack_kh(const float* __restrict__ in, _Float16* __restrict__ out)
{
    const int i = blockIdx.x * 256 + threadIdx.x;
    const float4 a = reinterpret_cast<const float4*>(in)[i * 2];
    const float4 b = reinterpret_cast<const float4*>(in)[i * 2 + 1];
    f16x8 r;
    r[0] = (_Float16)a.x; r[1] = (_Float16)a.y; r[2] = (_Float16)a.z; r[3] = (_Float16)a.w;
    r[4] = (_Float16)b.x; r[5] = (_Float16)b.y; r[6] = (_Float16)b.z; r[7] = (_Float16)b.w;
    *reinterpret_cast<f16x8*>(out + (size_t)i * 8) = r;
}

// ---------------------------------------------------------------------------
// Pack vbuf fp32 [b*S][g*64+d] -> vT fp16 [b][g][d][S] (transposed per head).
// ---------------------------------------------------------------------------
__global__ __launch_bounds__(256)
void pack_vT(const float* __restrict__ vbuf, _Float16* __restrict__ vT)
{
    __shared__ float tile[32][33];
    const int s0 = blockIdx.x * 32;
    const int d0 = blockIdx.y * 32;
    const int bg = blockIdx.z;               // b*8+g
    const int b  = bg >> 3, g = bg & 7;
    const int tx = threadIdx.x & 31, ty = threadIdx.x >> 5;
#pragma unroll
    for (int p = 0; p < 4; ++p) {
        const int r = ty + p * 8;
        tile[r][tx] = vbuf[(size_t)(b * Sseq + s0 + r) * NKVc + g * HDm + d0 + tx];
    }
    __syncthreads();
#pragma unroll
    for (int p = 0; p < 4; ++p) {
        const int dd = ty + p * 8;
        vT[((size_t)bg * HDm + d0 + dd) * Sseq + s0 + tx] = (_Float16)tile[tx][dd];
    }
}

// ---------------------------------------------------------------------------
// MFMA flash attention, fp16 inputs / fp32 softmax+accum, causal, GQA.
// Block: 64 q-rows x head x batch; 4 waves, each wave 16 q-rows.
// K tile [64 kcol][64 d], V^T tile [64 d][64 k] in LDS, XOR-swizzled (T2).
// P re-shaped acc->A-frag via per-wave 2KB LDS (wave-local, no barrier).
// Epilogue writes attention output directly as bf16 hi/lo for the out-proj.
// ---------------------------------------------------------------------------
__global__ __launch_bounds__(256)
void flash_mfma(const float* __restrict__ Qb, const _Float16* __restrict__ Kh,
                const _Float16* __restrict__ Vt,
                ushort* __restrict__ aohi, ushort* __restrict__ aolo,
                const int* __restrict__ spp)
{
    __shared__ _Float16 Ks[64 * 64];
    __shared__ _Float16 Vs[64 * 64];
    __shared__ _Float16 Ps[4][16 * 64];

    const int qb = blockIdx.x;
    const int h  = blockIdx.y;
    const int b  = blockIdx.z;
    const int g  = h >> 2;
    const int sp = *spp;
    const int t  = threadIdx.x;
    const int lane = t & 63;
    const int wid  = t >> 6;
    const int fr = lane & 15;     // fragment row/col within 16
    const int fq = lane >> 4;     // quarter (k-chunk / acc row group)

    // Q A-fragments: rows wid*16+fr, pre-scaled by 1/8, fp32 -> fp16
    f16x8 qf[2];
    {
        const float* qp = Qb + (size_t)(b * Sseq + qb * 64 + wid * 16 + fr) * NQc + h * HDm;
#pragma unroll
        for (int c = 0; c < 2; ++c) {
            const float4 v0 = *reinterpret_cast<const float4*>(qp + c * 32 + fq * 8);
            const float4 v1 = *reinterpret_cast<const float4*>(qp + c * 32 + fq * 8 + 4);
            f16x8 q;
            q[0] = (_Float16)(v0.x * 0.125f); q[1] = (_Float16)(v0.y * 0.125f);
            q[2] = (_Float16)(v0.z * 0.125f); q[3] = (_Float16)(v0.w * 0.125f);
            q[4] = (_Float16)(v1.x * 0.125f); q[5] = (_Float16)(v1.y * 0.125f);
            q[6] = (_Float16)(v1.z * 0.125f); q[7] = (_Float16)(v1.w * 0.125f);
            qf[c] = q;
        }
    }

    f32x4 accO[4];
    float m_i[4], l_i[4];
#pragma unroll
    for (int n = 0; n < 4; ++n) accO[n] = (f32x4){0.f, 0.f, 0.f, 0.f};
#pragma unroll
    for (int j = 0; j < 4; ++j) { m_i[j] = -1e30f; l_i[j] = 0.f; }

    const int nkb = min(Sseq >> 6, ((qb * 64 + 63 + sp) >> 6) + 1);

    for (int kb = 0; kb < nkb; ++kb) {
        __syncthreads();   // all waves done reading Ks/Vs from prev iter
        // Stage K [kcol][d] and V^T [d][k], both 64x64 fp16, XOR-swizzled.
#pragma unroll
        for (int c2 = 0; c2 < 2; ++c2) {
            const int idx = t + c2 * 256;
            const int r  = idx >> 3;       // row (kcol for K, d for Vt)
            const int ch = idx & 7;        // 16B chunk within row
            const int sw = (ch ^ (r & 7)) << 3;
            const uint4 kv = *reinterpret_cast<const uint4*>(
                Kh + (size_t)(b * Sseq + kb * 64 + r) * NKVc + g * HDm + ch * 8);
            *reinterpret_cast<uint4*>(&Ks[r * 64 + sw]) = kv;
            const uint4 vv = *reinterpret_cast<const uint4*>(
                Vt + ((size_t)(b * Hkv + g) * HDm + r) * Sseq + kb * 64 + ch * 8);
            *reinterpret_cast<uint4*>(&Vs[r * 64 + sw]) = vv;
        }
        __syncthreads();

        // S = Q K^T : acc col = kcol(n*16+fr), row = q(fq*4+j)
        f32x4 accS[4];
#pragma unroll
        for (int n = 0; n < 4; ++n) accS[n] = (f32x4){0.f, 0.f, 0.f, 0.f};
#pragma unroll
        for (int n = 0; n < 4; ++n)
#pragma unroll
            for (int c = 0; c < 2; ++c) {
                const int r  = n * 16 + fr;
                const int cc = c * 4 + fq;
                const f16x8 kf = *reinterpret_cast<const f16x8*>(
                    &Ks[r * 64 + ((cc ^ (r & 7)) << 3)]);
                accS[n] = __builtin_amdgcn_mfma_f32_16x16x32_f16(qf[c], kf, accS[n], 0, 0, 0);
            }

        // Causal mask (diagonal block only)
        if (kb * 64 + 63 > qb * 64 + sp) {
            const int q0 = sp + qb * 64 + wid * 16 + fq * 4;
            const int k0 = kb * 64 + fr;
#pragma unroll
            for (int n = 0; n < 4; ++n)
#pragma unroll
                for (int j = 0; j < 4; ++j)
                    if (k0 + n * 16 > q0 + j) accS[n][j] = -1e30f;
        }

        // Online softmax (rows on (fq,j); reduce across 16 fr-lanes)
#pragma unroll
        for (int j = 0; j < 4; ++j) {
            float mx = fmaxf(fmaxf(accS[0][j], accS[1][j]), fmaxf(accS[2][j], accS[3][j]));
#pragma unroll
            for (int msk = 1; msk < 16; msk <<= 1)
                mx = fmaxf(mx, __shfl_xor(mx, msk));
            const float mnew = fmaxf(m_i[j], mx);
            const float corr = __expf(m_i[j] - mnew);
            m_i[j] = mnew;
            float rs = 0.f;
#pragma unroll
            for (int n = 0; n < 4; ++n) {
                const float p = __expf(accS[n][j] - mnew);
                accS[n][j] = p;
                rs += p;
            }
#pragma unroll
            for (int msk = 1; msk < 16; msk <<= 1)
                rs += __shfl_xor(rs, msk);
            l_i[j] = l_i[j] * corr + rs;
#pragma unroll
            for (int n = 0; n < 4; ++n) accO[n][j] *= corr;
            // write P row (row = fq*4+j, col = n*16+fr), swizzled
            const int prow = fq * 4 + j;
#pragma unroll
            for (int n = 0; n < 4; ++n) {
                const int col = n * 16 + fr;
                Ps[wid][prow * 64 + (((col >> 3) ^ (prow & 7)) << 3) + (col & 7)] =
                    (_Float16)accS[n][j];
            }
        }

        // P A-fragments (wave-local LDS, ordered by lgkmcnt — no barrier)
        f16x8 pa[2];
#pragma unroll
        for (int c = 0; c < 2; ++c) {
            const int cc = c * 4 + fq;
            pa[c] = *reinterpret_cast<const f16x8*>(
                &Ps[wid][fr * 64 + ((cc ^ (fr & 7)) << 3)]);
        }
        // O += P V  : acc col = d(n*16+fr), row = q(fq*4+j)
#pragma unroll
        for (int n = 0; n < 4; ++n)
#pragma unroll
            for (int c = 0; c < 2; ++c) {
                const int r  = n * 16 + fr;
                const int cc = c * 4 + fq;
                const f16x8 vf = *reinterpret_cast<const f16x8*>(
                    &Vs[r * 64 + ((cc ^ (r & 7)) << 3)]);
                accO[n] = __builtin_amdgcn_mfma_f32_16x16x32_f16(pa[c], vf, accO[n], 0, 0, 0);
            }
    }

    // Epilogue: normalize, write bf16 hi/lo attention output
#pragma unroll
    for (int j = 0; j < 4; ++j) {
        const float inv = 1.0f / l_i[j];
        const size_t rowg = (size_t)(b * Sseq + qb * 64 + wid * 16 + fq * 4 + j) * NQc;
#pragma unroll
        for (int n = 0; n < 4; ++n) {
            const int col = h * HDm + n * 16 + fr;
            const float o = accO[n][j] * inv;
            const ushort hb = f2bf(o);
            aohi[rowg + col] = hb;
            aolo[rowg + col] = f2bf(o - bf2f(hb));
        }
    }
}

// ---------------------------------------------------------------------------
// Launcher. Workspace (80 MB, aliased):
//  0..16  wqT hi/lo | 16..20 kh,vT fp16 (alias wkT after use)
//  16..24 wkT/wvT hi/lo (dead after gemm_qkv)
//  24..40 woT hi/lo | 40..56 aohi/aolo (alias xhi/xlo, dead after gemm_qkv)
//  56..72 qbuf | 72..76 kbuf | 76..80 vbuf
// ---------------------------------------------------------------------------
extern "C" void kernel_launch(void* const* d_in, const int* in_sizes, int n_in,
                              void* d_out, int out_size, void* d_ws, size_t ws_size,
                              hipStream_t stream)
{
    const float* x    = (const float*)d_in[0];
    const float* wq   = (const float*)d_in[1];
    const float* wk   = (const float*)d_in[2];
    const float* wv   = (const float*)d_in[3];
    const float* wo   = (const float*)d_in[4];
    const float* cosT = (const float*)d_in[5];
    const float* sinT = (const float*)d_in[6];
    const int*   spp  = (const int*)d_in[7];
    float*       out  = (float*)d_out;

    char* w = (char*)d_ws;
    ushort*   wqThi = (ushort*)(w);
    ushort*   wqTlo = (ushort*)(w + (8ull  << 20));
    ushort*   wkThi = (ushort*)(w + (16ull << 20));
    ushort*   wkTlo = (ushort*)(w + (18ull << 20));
    ushort*   wvThi = (ushort*)(w + (20ull << 20));
    ushort*   wvTlo = (ushort*)(w + (22ull << 20));
    ushort*   woThi = (ushort*)(w + (24ull << 20));
    ushort*   woTlo = (ushort*)(w + (32ull << 20));
    ushort*   xhi   = (ushort*)(w + (40ull << 20));
    ushort*   xlo   = (ushort*)(w + (48ull << 20));
    ushort*   aohi  = (ushort*)(w + (40ull << 20));   // alias xhi (dead post-QKV)
    ushort*   aolo  = (ushort*)(w + (48ull << 20));   // alias xlo
    _Float16* kh    = (_Float16*)(w + (16ull << 20)); // alias wkThi (dead post-QKV)
    _Float16* vT    = (_Float16*)(w + (18ull << 20)); // alias wkTlo
    float*    qbuf  = (float*)(w + (56ull << 20));
    float*    kbuf  = (float*)(w + (72ull << 20));
    float*    vbuf  = (float*)(w + (76ull << 20));

    // hi/lo conversions
    conv_split<<<2048, 256, 0, stream>>>(x, xhi, xlo);
    conv_split_t<<<dim3(64, 64), 256, 0, stream>>>(wq, wqThi, wqTlo, Ddim, NQc);
    conv_split_t<<<dim3(16, 64), 256, 0, stream>>>(wk, wkThi, wkTlo, Ddim, NKVc);
    conv_split_t<<<dim3(16, 64), 256, 0, stream>>>(wv, wvThi, wvTlo, Ddim, NKVc);
    conv_split_t<<<dim3(64, 64), 256, 0, stream>>>(wo, woThi, woTlo, NQc, Ddim);

    // Fused QKV projection (one dispatch, 384 blocks)
    gemm_qkv<<<dim3(24, 16), 256, 0, stream>>>(xhi, xlo,
                                               wqThi, wqTlo, wkThi, wkTlo, wvThi, wvTlo,
                                               qbuf, kbuf, vbuf);

    // RoPE (fp32, in place)
    rope_kernel<<<(MROWS * (Hq + Hkv) * 32) / 256, 256, 0, stream>>>(qbuf, kbuf, cosT, sinT);

    // Pack K (post-RoPE) -> fp16; V -> fp16 transposed per head
    pack_kh<<<512, 256, 0, stream>>>(kbuf, kh);
    pack_vT<<<dim3(32, 2, 16), 256, 0, stream>>>(vbuf, vT);

    // MFMA flash attention (writes bf16 hi/lo directly)
    flash_mfma<<<dim3(Sseq / 64, Hq, Bsz), 256, 0, stream>>>(qbuf, kh, vT, aohi, aolo, spp);

    // Output projection
    gemm_split<<<dim3(16, 16), 256, 0, stream>>>(aohi, aolo, woThi, woTlo, out, Ddim, NQc);
}

// Round 5
// 322.077 us; speedup vs baseline: 4.1664x; 1.1396x over previous
//
#include <hip/hip_runtime.h>
#include <cstdint>
#include <cstddef>

// Problem constants
#define Bsz   2
#define Sseq  1024
#define Ddim  2048
#define Hq    32
#define Hkv   8
#define HDm   64
#define MROWS (Bsz * Sseq)   // 2048
#define NQc   (Hq * HDm)     // 2048
#define NKVc  (Hkv * HDm)    // 512

typedef __attribute__((ext_vector_type(8))) _Float16 f16x8;
typedef __attribute__((ext_vector_type(4))) float    f32x4;

// async global->LDS, 16B per lane; LDS dest is wave-uniform base + lane*16
__device__ __forceinline__ void gload_lds16(const void* g, void* s) {
    __builtin_amdgcn_global_load_lds(
        (const __attribute__((address_space(1))) void*)g,
        (__attribute__((address_space(3))) void*)s, 16, 0, 0);
}

// ---------------------------------------------------------------------------
// fp32 -> fp16 hi/lo split, same layout. One thread per 8 floats.
// hi = RNE fp16(x); lo = fp16(x - hi). hi+lo captures fp32 to ~2^-22 rel.
// ---------------------------------------------------------------------------
__global__ __launch_bounds__(256)
void conv_split16(const float* __restrict__ in, _Float16* __restrict__ hi,
                  _Float16* __restrict__ lo)
{
    const int i = blockIdx.x * 256 + threadIdx.x;
    const float4 v0 = reinterpret_cast<const float4*>(in)[i * 2];
    const float4 v1 = reinterpret_cast<const float4*>(in)[i * 2 + 1];
    const float a[8] = {v0.x, v0.y, v0.z, v0.w, v1.x, v1.y, v1.z, v1.w};
    f16x8 h, l;
#pragma unroll
    for (int j = 0; j < 8; ++j) {
        const _Float16 hh = (_Float16)a[j];
        h[j] = hh;
        l[j] = (_Float16)(a[j] - (float)hh);
    }
    *reinterpret_cast<f16x8*>(hi + (size_t)i * 8) = h;
    *reinterpret_cast<f16x8*>(lo + (size_t)i * 8) = l;
}

// ---------------------------------------------------------------------------
// All 4 weight matrices fp32 [R][C] -> single fp16 transposed [C][R].
// One dispatch; linear block id selects {wq, wk, wv, wo} + 32x32 tile.
// ---------------------------------------------------------------------------
__global__ __launch_bounds__(256)
void conv_w16t(const float* __restrict__ wq, const float* __restrict__ wk,
               const float* __restrict__ wv, const float* __restrict__ wo,
               _Float16* __restrict__ oq, _Float16* __restrict__ ok,
               _Float16* __restrict__ ov, _Float16* __restrict__ oo)
{
    __shared__ float tile[32][33];
    const int id = blockIdx.x;
    const float* src; _Float16* dst; int C, t;
    if (id < 4096)      { src = wq; dst = oq; C = 2048; t = id; }
    else if (id < 5120) { src = wk; dst = ok; C = 512;  t = id - 4096; }
    else if (id < 6144) { src = wv; dst = ov; C = 512;  t = id - 5120; }
    else                { src = wo; dst = oo; C = 2048; t = id - 6144; }
    const int R = 2048;
    const int ctiles = C >> 5;
    const int c0 = (t % ctiles) * 32, r0 = (t / ctiles) * 32;
    const int tx = threadIdx.x & 31, ty = threadIdx.x >> 5;
#pragma unroll
    for (int p = 0; p < 4; ++p) {
        const int r = ty + p * 8;
        tile[r][tx] = src[(size_t)(r0 + r) * C + c0 + tx];
    }
    __syncthreads();
#pragma unroll
    for (int p = 0; p < 4; ++p) {
        const int cc = ty + p * 8;
        dst[(size_t)(c0 + cc) * R + r0 + tx] = (_Float16)tile[tx][cc];
    }
}

// ---------------------------------------------------------------------------
// 2-MFMA fp16-split GEMM main loop (128x128 tile, BK=32, 4 waves).
// C = Ahi*B + Alo*B ; A hi/lo fp16 [M][K], B single fp16 [N][K].
// Error = B fp16 quantization only (~2^-12 rel) — A captured to fp32 grade.
// ---------------------------------------------------------------------------
__device__ __forceinline__
void gemm2_loop(const _Float16* __restrict__ Ahi, const _Float16* __restrict__ Alo,
                const _Float16* __restrict__ Bt, int Kdim, int row0, int col0,
                _Float16* sAhi, _Float16* sAlo, _Float16* sB,
                f32x4 (&acc)[4][4])
{
    const int t    = threadIdx.x;
    const int lane = t & 63;
    const int wid  = t >> 6;
    const int wr   = wid >> 1;
    const int wc   = wid & 1;
    const int fr   = lane & 15;
    const int kc   = (lane >> 4) * 8;

    for (int k0 = 0; k0 < Kdim; k0 += 32) {
        __syncthreads();
        // Stage A hi/lo (8KB each) + B (8KB): 6 x 1KB gload_lds per thread-set
#pragma unroll
        for (int c = 0; c < 2; ++c) {
            const int rr = (wid * 2 + c) * 16 + (lane >> 2);
            const int cb = (lane & 3) * 8;
            const size_t ga = (size_t)(row0 + rr) * Kdim + k0 + cb;
            const size_t gb = (size_t)(col0 + rr) * Kdim + k0 + cb;
            gload_lds16(Ahi + ga, (char*)sAhi + (wid * 2 + c) * 1024);
            gload_lds16(Alo + ga, (char*)sAlo + (wid * 2 + c) * 1024);
            gload_lds16(Bt  + gb, (char*)sB   + (wid * 2 + c) * 1024);
        }
        __syncthreads();

        f16x8 ah[4], al[4], bb[4];
        const int ar = wr * 64 + fr;
        const int br = wc * 64 + fr;
#pragma unroll
        for (int m = 0; m < 4; ++m) {
            ah[m] = *reinterpret_cast<const f16x8*>(&sAhi[(ar + m * 16) * 32 + kc]);
            al[m] = *reinterpret_cast<const f16x8*>(&sAlo[(ar + m * 16) * 32 + kc]);
        }
#pragma unroll
        for (int n = 0; n < 4; ++n)
            bb[n] = *reinterpret_cast<const f16x8*>(&sB[(br + n * 16) * 32 + kc]);
#pragma unroll
        for (int m = 0; m < 4; ++m)
#pragma unroll
            for (int n = 0; n < 4; ++n) {
                acc[m][n] = __builtin_amdgcn_mfma_f32_16x16x32_f16(ah[m], bb[n], acc[m][n], 0, 0, 0);
                acc[m][n] = __builtin_amdgcn_mfma_f32_16x16x32_f16(al[m], bb[n], acc[m][n], 0, 0, 0);
            }
    }
}

// ---------------------------------------------------------------------------
// Fused QKV projection + RoPE epilogue.
// grid.x: 0..15 -> q (RoPE, *0.125, fp16 out), 16..19 -> k (RoPE, fp16 out),
//         20..23 -> v (fp32 out). Each wave's 64-col span = one head, so both
//         RoPE partners (d, d+32) live in-register: n pairs (0,2) and (1,3).
// ---------------------------------------------------------------------------
__global__ __launch_bounds__(256)
void gemm_qkv2(const _Float16* __restrict__ xhi, const _Float16* __restrict__ xlo,
               const _Float16* __restrict__ wqT, const _Float16* __restrict__ wkT,
               const _Float16* __restrict__ wvT,
               const float* __restrict__ cosT, const float* __restrict__ sinT,
               _Float16* __restrict__ qh, _Float16* __restrict__ kh,
               float* __restrict__ vbuf)
{
    __shared__ _Float16 sAhi[128 * 32];
    __shared__ _Float16 sAlo[128 * 32];
    __shared__ _Float16 sB[128 * 32];

    const int bx   = blockIdx.x;
    const int row0 = blockIdx.y * 128;
    const _Float16* Bt; int col0, mode;
    if (bx < 16)      { Bt = wqT; col0 = bx * 128;        mode = 0; }
    else if (bx < 20) { Bt = wkT; col0 = (bx - 16) * 128; mode = 1; }
    else              { Bt = wvT; col0 = (bx - 20) * 128; mode = 2; }

    f32x4 acc[4][4];
#pragma unroll
    for (int m = 0; m < 4; ++m)
#pragma unroll
        for (int n = 0; n < 4; ++n)
            acc[m][n] = (f32x4){0.f, 0.f, 0.f, 0.f};

    gemm2_loop(xhi, xlo, Bt, Ddim, row0, col0, sAhi, sAlo, sB, acc);

    const int lane = threadIdx.x & 63;
    const int wid  = threadIdx.x >> 6;
    const int wr   = wid >> 1, wc = wid & 1;
    const int fr   = lane & 15, fq = lane >> 4;

    if (mode == 2) {
        // v: plain fp32 store
#pragma unroll
        for (int m = 0; m < 4; ++m)
#pragma unroll
            for (int j = 0; j < 4; ++j) {
                const int row = row0 + wr * 64 + m * 16 + fq * 4 + j;
                float* vp = vbuf + (size_t)row * NKVc + col0 + wc * 64 + fr;
#pragma unroll
                for (int n = 0; n < 4; ++n) vp[n * 16] = acc[m][n][j];
            }
    } else {
        _Float16* dst = (mode == 0) ? qh : kh;
        const int ldd = (mode == 0) ? NQc : NKVc;
        const float qs = (mode == 0) ? 0.125f : 1.0f;
        const int colb = col0 + wc * 64;
#pragma unroll
        for (int m = 0; m < 4; ++m)
#pragma unroll
            for (int j = 0; j < 4; ++j) {
                const int row = row0 + wr * 64 + m * 16 + fq * 4 + j;
                const int s   = row & (Sseq - 1);
                const float c0 = cosT[s * HDm + fr],      s0 = sinT[s * HDm + fr];
                const float c1 = cosT[s * HDm + 16 + fr], s1 = sinT[s * HDm + 16 + fr];
                const float o0 = acc[m][0][j], o1 = acc[m][1][j];
                const float o2 = acc[m][2][j], o3 = acc[m][3][j];
                _Float16* bp = dst + (size_t)row * ldd + colb;
                bp[fr]      = (_Float16)((o0 * c0 - o2 * s0) * qs);
                bp[16 + fr] = (_Float16)((o1 * c1 - o3 * s1) * qs);
                bp[32 + fr] = (_Float16)((o2 * c0 + o0 * s0) * qs);
                bp[48 + fr] = (_Float16)((o3 * c1 + o1 * s1) * qs);
            }
    }
}

// ---------------------------------------------------------------------------
// Output projection: 2-MFMA fp16-split, fp32 C.
// ---------------------------------------------------------------------------
__global__ __launch_bounds__(256)
void gemm_out2(const _Float16* __restrict__ aohi, const _Float16* __restrict__ aolo,
               const _Float16* __restrict__ woT, float* __restrict__ C)
{
    __shared__ _Float16 sAhi[128 * 32];
    __shared__ _Float16 sAlo[128 * 32];
    __shared__ _Float16 sB[128 * 32];

    const int row0 = blockIdx.y * 128;
    const int col0 = blockIdx.x * 128;

    f32x4 acc[4][4];
#pragma unroll
    for (int m = 0; m < 4; ++m)
#pragma unroll
        for (int n = 0; n < 4; ++n)
            acc[m][n] = (f32x4){0.f, 0.f, 0.f, 0.f};

    gemm2_loop(aohi, aolo, woT, NQc, row0, col0, sAhi, sAlo, sB, acc);

    const int lane = threadIdx.x & 63;
    const int wid  = threadIdx.x >> 6;
    const int wr   = wid >> 1, wc = wid & 1;
    const int fr   = lane & 15, fq = lane >> 4;
#pragma unroll
    for (int m = 0; m < 4; ++m)
#pragma unroll
        for (int j = 0; j < 4; ++j) {
            float* cp = C + (size_t)(row0 + wr * 64 + m * 16 + fq * 4 + j) * Ddim
                          + col0 + wc * 64 + fr;
#pragma unroll
            for (int n = 0; n < 4; ++n) cp[n * 16] = acc[m][n][j];
        }
}

// ---------------------------------------------------------------------------
// Pack vbuf fp32 [b*S][g*64+d] -> vT fp16 [b][g][d][S] (transposed per head).
// ---------------------------------------------------------------------------
__global__ __launch_bounds__(256)
void pack_vT(const float* __restrict__ vbuf, _Float16* __restrict__ vT)
{
    __shared__ float tile[32][33];
    const int s0 = blockIdx.x * 32;
    const int d0 = blockIdx.y * 32;
    const int bg = blockIdx.z;               // b*8+g
    const int b  = bg >> 3, g = bg & 7;
    const int tx = threadIdx.x & 31, ty = threadIdx.x >> 5;
#pragma unroll
    for (int p = 0; p < 4; ++p) {
        const int r = ty + p * 8;
        tile[r][tx] = vbuf[(size_t)(b * Sseq + s0 + r) * NKVc + g * HDm + d0 + tx];
    }
    __syncthreads();
#pragma unroll
    for (int p = 0; p < 4; ++p) {
        const int dd = ty + p * 8;
        vT[((size_t)bg * HDm + d0 + dd) * Sseq + s0 + tx] = (_Float16)tile[tx][dd];
    }
}

// ---------------------------------------------------------------------------
// MFMA flash attention, fp16 inputs / fp32 softmax+accum, causal, GQA.
// Q read directly as fp16 (RoPE'd + pre-scaled by gemm_qkv2 epilogue).
// K tile [64 kcol][64 d], V^T tile [64 d][64 k] in LDS, XOR-swizzled (T2).
// P re-shaped acc->A-frag via per-wave 2KB LDS (wave-local, no barrier).
// Writes ao fp32.
// ---------------------------------------------------------------------------
__global__ __launch_bounds__(256)
void flash_mfma(const _Float16* __restrict__ Qh, const _Float16* __restrict__ Kh,
                const _Float16* __restrict__ Vt, float* __restrict__ ao,
                const int* __restrict__ spp)
{
    __shared__ _Float16 Ks[64 * 64];
    __shared__ _Float16 Vs[64 * 64];
    __shared__ _Float16 Ps[4][16 * 64];

    const int qb = blockIdx.x;
    const int h  = blockIdx.y;
    const int b  = blockIdx.z;
    const int g  = h >> 2;
    const int sp = *spp;
    const int t  = threadIdx.x;
    const int lane = t & 63;
    const int wid  = t >> 6;
    const int fr = lane & 15;
    const int fq = lane >> 4;

    // Q A-fragments, direct fp16 load
    f16x8 qf[2];
    {
        const _Float16* qp = Qh + (size_t)(b * Sseq + qb * 64 + wid * 16 + fr) * NQc + h * HDm;
#pragma unroll
        for (int c = 0; c < 2; ++c)
            qf[c] = *reinterpret_cast<const f16x8*>(qp + c * 32 + fq * 8);
    }

    f32x4 accO[4];
    float m_i[4], l_i[4];
#pragma unroll
    for (int n = 0; n < 4; ++n) accO[n] = (f32x4){0.f, 0.f, 0.f, 0.f};
#pragma unroll
    for (int j = 0; j < 4; ++j) { m_i[j] = -1e30f; l_i[j] = 0.f; }

    const int nkb = min(Sseq >> 6, ((qb * 64 + 63 + sp) >> 6) + 1);

    for (int kb = 0; kb < nkb; ++kb) {
        __syncthreads();
#pragma unroll
        for (int c2 = 0; c2 < 2; ++c2) {
            const int idx = t + c2 * 256;
            const int r  = idx >> 3;
            const int ch = idx & 7;
            const int sw = (ch ^ (r & 7)) << 3;
            const uint4 kv = *reinterpret_cast<const uint4*>(
                Kh + (size_t)(b * Sseq + kb * 64 + r) * NKVc + g * HDm + ch * 8);
            *reinterpret_cast<uint4*>(&Ks[r * 64 + sw]) = kv;
            const uint4 vv = *reinterpret_cast<const uint4*>(
                Vt + ((size_t)(b * Hkv + g) * HDm + r) * Sseq + kb * 64 + ch * 8);
            *reinterpret_cast<uint4*>(&Vs[r * 64 + sw]) = vv;
        }
        __syncthreads();

        // S = Q K^T : acc col = kcol(n*16+fr), row = q(fq*4+j)
        f32x4 accS[4];
#pragma unroll
        for (int n = 0; n < 4; ++n) accS[n] = (f32x4){0.f, 0.f, 0.f, 0.f};
#pragma unroll
        for (int n = 0; n < 4; ++n)
#pragma unroll
            for (int c = 0; c < 2; ++c) {
                const int r  = n * 16 + fr;
                const int cc = c * 4 + fq;
                const f16x8 kf = *reinterpret_cast<const f16x8*>(
                    &Ks[r * 64 + ((cc ^ (r & 7)) << 3)]);
                accS[n] = __builtin_amdgcn_mfma_f32_16x16x32_f16(qf[c], kf, accS[n], 0, 0, 0);
            }

        // Causal mask (diagonal block only)
        if (kb * 64 + 63 > qb * 64 + sp) {
            const int q0 = sp + qb * 64 + wid * 16 + fq * 4;
            const int k0 = kb * 64 + fr;
#pragma unroll
            for (int n = 0; n < 4; ++n)
#pragma unroll
                for (int j = 0; j < 4; ++j)
                    if (k0 + n * 16 > q0 + j) accS[n][j] = -1e30f;
        }

        // Online softmax (rows on (fq,j); reduce across 16 fr-lanes)
#pragma unroll
        for (int j = 0; j < 4; ++j) {
            float mx = fmaxf(fmaxf(accS[0][j], accS[1][j]), fmaxf(accS[2][j], accS[3][j]));
#pragma unroll
            for (int msk = 1; msk < 16; msk <<= 1)
                mx = fmaxf(mx, __shfl_xor(mx, msk));
            const float mnew = fmaxf(m_i[j], mx);
            const float corr = __expf(m_i[j] - mnew);
            m_i[j] = mnew;
            float rs = 0.f;
#pragma unroll
            for (int n = 0; n < 4; ++n) {
                const float p = __expf(accS[n][j] - mnew);
                accS[n][j] = p;
                rs += p;
            }
#pragma unroll
            for (int msk = 1; msk < 16; msk <<= 1)
                rs += __shfl_xor(rs, msk);
            l_i[j] = l_i[j] * corr + rs;
#pragma unroll
            for (int n = 0; n < 4; ++n) accO[n][j] *= corr;
            const int prow = fq * 4 + j;
#pragma unroll
            for (int n = 0; n < 4; ++n) {
                const int col = n * 16 + fr;
                Ps[wid][prow * 64 + (((col >> 3) ^ (prow & 7)) << 3) + (col & 7)] =
                    (_Float16)accS[n][j];
            }
        }

        // P A-fragments (wave-local LDS, ordered by lgkmcnt — no barrier)
        f16x8 pa[2];
#pragma unroll
        for (int c = 0; c < 2; ++c) {
            const int cc = c * 4 + fq;
            pa[c] = *reinterpret_cast<const f16x8*>(
                &Ps[wid][fr * 64 + ((cc ^ (fr & 7)) << 3)]);
        }
        // O += P V : acc col = d(n*16+fr), row = q(fq*4+j)
#pragma unroll
        for (int n = 0; n < 4; ++n)
#pragma unroll
            for (int c = 0; c < 2; ++c) {
                const int r  = n * 16 + fr;
                const int cc = c * 4 + fq;
                const f16x8 vf = *reinterpret_cast<const f16x8*>(
                    &Vs[r * 64 + ((cc ^ (r & 7)) << 3)]);
                accO[n] = __builtin_amdgcn_mfma_f32_16x16x32_f16(pa[c], vf, accO[n], 0, 0, 0);
            }
    }

    // Epilogue: normalize, write ao fp32
#pragma unroll
    for (int j = 0; j < 4; ++j) {
        const float inv = 1.0f / l_i[j];
        const size_t rowg = (size_t)(b * Sseq + qb * 64 + wid * 16 + fq * 4 + j) * NQc;
#pragma unroll
        for (int n = 0; n < 4; ++n)
            ao[rowg + h * HDm + n * 16 + fr] = accO[n][j] * inv;
    }
}

// ---------------------------------------------------------------------------
// Launcher. Workspace (68 MB):
//  0..8 wqT16 | 8..10 wkT16 | 10..12 wvT16 | 12..20 woT16
//  20..28 xhi (later aohi) | 28..36 xlo (later aolo)
//  36..44 qh | 44..46 kh | 46..50 vbuf | 50..52 vT | 52..68 ao
// ---------------------------------------------------------------------------
extern "C" void kernel_launch(void* const* d_in, const int* in_sizes, int n_in,
                              void* d_out, int out_size, void* d_ws, size_t ws_size,
                              hipStream_t stream)
{
    const float* x    = (const float*)d_in[0];
    const float* wq   = (const float*)d_in[1];
    const float* wk   = (const float*)d_in[2];
    const float* wv   = (const float*)d_in[3];
    const float* wo   = (const float*)d_in[4];
    const float* cosT = (const float*)d_in[5];
    const float* sinT = (const float*)d_in[6];
    const int*   spp  = (const int*)d_in[7];
    float*       out  = (float*)d_out;

    char* w = (char*)d_ws;
    _Float16* wqT16 = (_Float16*)(w);
    _Float16* wkT16 = (_Float16*)(w + (8ull  << 20));
    _Float16* wvT16 = (_Float16*)(w + (10ull << 20));
    _Float16* woT16 = (_Float16*)(w + (12ull << 20));
    _Float16* xhi   = (_Float16*)(w + (20ull << 20));
    _Float16* xlo   = (_Float16*)(w + (28ull << 20));
    _Float16* aohi  = (_Float16*)(w + (20ull << 20));  // alias xhi (dead post-QKV)
    _Float16* aolo  = (_Float16*)(w + (28ull << 20));  // alias xlo
    _Float16* qh    = (_Float16*)(w + (36ull << 20));
    _Float16* kh    = (_Float16*)(w + (44ull << 20));
    float*    vbuf  = (float*)   (w + (46ull << 20));
    _Float16* vT    = (_Float16*)(w + (50ull << 20));
    float*    ao    = (float*)   (w + (52ull << 20));

    // Input conversions
    conv_split16<<<2048, 256, 0, stream>>>(x, xhi, xlo);
    conv_w16t<<<10240, 256, 0, stream>>>(wq, wk, wv, wo, wqT16, wkT16, wvT16, woT16);

    // Fused QKV projection + RoPE (q fp16 pre-scaled, k fp16, v fp32)
    gemm_qkv2<<<dim3(24, 16), 256, 0, stream>>>(xhi, xlo, wqT16, wkT16, wvT16,
                                                cosT, sinT, qh, kh, vbuf);

    // V -> fp16 transposed per head
    pack_vT<<<dim3(32, 2, 16), 256, 0, stream>>>(vbuf, vT);

    // MFMA flash attention
    flash_mfma<<<dim3(Sseq / 64, Hq, Bsz), 256, 0, stream>>>(qh, kh, vT, ao, spp);

    // Output projection
    conv_split16<<<2048, 256, 0, stream>>>(ao, aohi, aolo);
    gemm_out2<<<dim3(16, 16), 256, 0, stream>>>(aohi, aolo, woT16, out);
}

// Round 9
// 279.276 us; speedup vs baseline: 4.8049x; 1.1533x over previous
//
#include <hip/hip_runtime.h>
#include <cstdint>
#include <cstddef>

// Problem constants
#define Bsz   2
#define Sseq  1024
#define Ddim  2048
#define Hq    32
#define Hkv   8
#define HDm   64
#define MROWS (Bsz * Sseq)   // 2048
#define NQc   (Hq * HDm)     // 2048
#define NKVc  (Hkv * HDm)    // 512

typedef __attribute__((ext_vector_type(8))) _Float16 f16x8;
typedef __attribute__((ext_vector_type(4))) float    f32x4;

// async global->LDS, 16B per lane; LDS dest is wave-uniform base + lane*16
__device__ __forceinline__ void gload_lds16(const void* g, void* s) {
    __builtin_amdgcn_global_load_lds(
        (const __attribute__((address_space(1))) void*)g,
        (__attribute__((address_space(3))) void*)s, 16, 0, 0);
}

// ---------------------------------------------------------------------------
// fp32 -> fp16 hi/lo split, same layout. One thread per 8 floats.
// ---------------------------------------------------------------------------
__global__ __launch_bounds__(256)
void conv_split16(const float* __restrict__ in, _Float16* __restrict__ hi,
                  _Float16* __restrict__ lo)
{
    const int i = blockIdx.x * 256 + threadIdx.x;
    const float4 v0 = reinterpret_cast<const float4*>(in)[i * 2];
    const float4 v1 = reinterpret_cast<const float4*>(in)[i * 2 + 1];
    const float a[8] = {v0.x, v0.y, v0.z, v0.w, v1.x, v1.y, v1.z, v1.w};
    f16x8 h, l;
#pragma unroll
    for (int j = 0; j < 8; ++j) {
        const _Float16 hh = (_Float16)a[j];
        h[j] = hh;
        l[j] = (_Float16)(a[j] - (float)hh);
    }
    *reinterpret_cast<f16x8*>(hi + (size_t)i * 8) = h;
    *reinterpret_cast<f16x8*>(lo + (size_t)i * 8) = l;
}

// ---------------------------------------------------------------------------
// All 4 weight matrices fp32 [R][C] -> single fp16 transposed [C][R].
// ---------------------------------------------------------------------------
__global__ __launch_bounds__(256)
void conv_w16t(const float* __restrict__ wq, const float* __restrict__ wk,
               const float* __restrict__ wv, const float* __restrict__ wo,
               _Float16* __restrict__ oq, _Float16* __restrict__ ok,
               _Float16* __restrict__ ov, _Float16* __restrict__ oo)
{
    __shared__ float tile[32][33];
    const int id = blockIdx.x;
    const float* src; _Float16* dst; int C, t;
    if (id < 4096)      { src = wq; dst = oq; C = 2048; t = id; }
    else if (id < 5120) { src = wk; dst = ok; C = 512;  t = id - 4096; }
    else if (id < 6144) { src = wv; dst = ov; C = 512;  t = id - 5120; }
    else                { src = wo; dst = oo; C = 2048; t = id - 6144; }
    const int R = 2048;
    const int ctiles = C >> 5;
    const int c0 = (t % ctiles) * 32, r0 = (t / ctiles) * 32;
    const int tx = threadIdx.x & 31, ty = threadIdx.x >> 5;
#pragma unroll
    for (int p = 0; p < 4; ++p) {
        const int r = ty + p * 8;
        tile[r][tx] = src[(size_t)(r0 + r) * C + c0 + tx];
    }
    __syncthreads();
#pragma unroll
    for (int p = 0; p < 4; ++p) {
        const int cc = ty + p * 8;
        dst[(size_t)(c0 + cc) * R + r0 + tx] = (_Float16)tile[tx][cc];
    }
}

// ---------------------------------------------------------------------------
// 2-MFMA fp16-split GEMM main loop, BM=64 x BN=128, BK=32, 4 waves (2x2).
// Each wave: 32 rows x 64 cols -> acc[2][4]; 16 MFMA + 4 gload_lds / k-step.
// Tile shrunk from 128x128 to raise blocks/CU (grid-limited occupancy fix).
// ---------------------------------------------------------------------------
__device__ __forceinline__
void gemm2_loop64(const _Float16* __restrict__ Ahi, const _Float16* __restrict__ Alo,
                  const _Float16* __restrict__ Bt, int Kdim, int row0, int col0,
                  _Float16* sAhi, _Float16* sAlo, _Float16* sB,
                  f32x4 (&acc)[2][4])
{
    const int t    = threadIdx.x;
    const int lane = t & 63;
    const int wid  = t >> 6;
    const int wr   = wid >> 1;
    const int wc   = wid & 1;
    const int fr   = lane & 15;
    const int kc   = (lane >> 4) * 8;
    const int srow = lane >> 2;           // staging row within 16-row segment
    const int scol = (lane & 3) * 8;      // staging col (8 fp16 = 16B)

    for (int k0 = 0; k0 < Kdim; k0 += 32) {
        __syncthreads();
        // A (64 rows): segment wid; B (128 rows): segments 2*wid, 2*wid+1
        {
            const size_t ga = (size_t)(row0 + wid * 16 + srow) * Kdim + k0 + scol;
            gload_lds16(Ahi + ga, (char*)sAhi + wid * 1024);
            gload_lds16(Alo + ga, (char*)sAlo + wid * 1024);
#pragma unroll
            for (int c = 0; c < 2; ++c) {
                const int seg = 2 * wid + c;
                const size_t gb = (size_t)(col0 + seg * 16 + srow) * Kdim + k0 + scol;
                gload_lds16(Bt + gb, (char*)sB + seg * 1024);
            }
        }
        __syncthreads();

        f16x8 ah[2], al[2], bb[4];
        const int ar = wr * 32 + fr;
        const int br = wc * 64 + fr;
#pragma unroll
        for (int m = 0; m < 2; ++m) {
            ah[m] = *reinterpret_cast<const f16x8*>(&sAhi[(ar + m * 16) * 32 + kc]);
            al[m] = *reinterpret_cast<const f16x8*>(&sAlo[(ar + m * 16) * 32 + kc]);
        }
#pragma unroll
        for (int n = 0; n < 4; ++n)
            bb[n] = *reinterpret_cast<const f16x8*>(&sB[(br + n * 16) * 32 + kc]);
#pragma unroll
        for (int m = 0; m < 2; ++m)
#pragma unroll
            for (int n = 0; n < 4; ++n) {
                acc[m][n] = __builtin_amdgcn_mfma_f32_16x16x32_f16(ah[m], bb[n], acc[m][n], 0, 0, 0);
                acc[m][n] = __builtin_amdgcn_mfma_f32_16x16x32_f16(al[m], bb[n], acc[m][n], 0, 0, 0);
            }
    }
}

// ---------------------------------------------------------------------------
// Fused QKV projection + RoPE epilogue + direct packing.
// grid: x = 24 col-tiles of 128 (0..15 q | 16..19 k | 20..23 v), y = 32 row-
// tiles of 64. q -> fp16 RoPE'd *0.125; k -> fp16 RoPE'd; v -> fp16 vT
// [b][g][d][S] (transposed direct write, deletes pack_vT).
// ---------------------------------------------------------------------------
__global__ __launch_bounds__(256)
void gemm_qkv2(const _Float16* __restrict__ xhi, const _Float16* __restrict__ xlo,
               const _Float16* __restrict__ wqT, const _Float16* __restrict__ wkT,
               const _Float16* __restrict__ wvT,
               const float* __restrict__ cosT, const float* __restrict__ sinT,
               _Float16* __restrict__ qh, _Float16* __restrict__ kh,
               _Float16* __restrict__ vT)
{
    __shared__ _Float16 sAhi[64 * 32];
    __shared__ _Float16 sAlo[64 * 32];
    __shared__ _Float16 sB[128 * 32];

    const int bx   = blockIdx.x;
    const int row0 = blockIdx.y * 64;
    const _Float16* Bt; int col0, mode;
    if (bx < 16)      { Bt = wqT; col0 = bx * 128;        mode = 0; }
    else if (bx < 20) { Bt = wkT; col0 = (bx - 16) * 128; mode = 1; }
    else              { Bt = wvT; col0 = (bx - 20) * 128; mode = 2; }

    f32x4 acc[2][4];
#pragma unroll
    for (int m = 0; m < 2; ++m)
#pragma unroll
        for (int n = 0; n < 4; ++n)
            acc[m][n] = (f32x4){0.f, 0.f, 0.f, 0.f};

    gemm2_loop64(xhi, xlo, Bt, Ddim, row0, col0, sAhi, sAlo, sB, acc);

    const int lane = threadIdx.x & 63;
    const int wid  = threadIdx.x >> 6;
    const int wr   = wid >> 1, wc = wid & 1;
    const int fr   = lane & 15, fq = lane >> 4;

    if (mode == 2) {
        // vT[(b*8+g)*64 + d][s], d = n*16+fr, g from wave's 64-col span
        const int gg = (col0 + wc * 64) >> 6;
#pragma unroll
        for (int m = 0; m < 2; ++m)
#pragma unroll
            for (int j = 0; j < 4; ++j) {
                const int row = row0 + wr * 32 + m * 16 + fq * 4 + j;
                const int b = row >> 10, s = row & (Sseq - 1);
#pragma unroll
                for (int n = 0; n < 4; ++n)
                    vT[(((size_t)((b * 8 + gg) * 64 + n * 16 + fr)) << 10) + s] =
                        (_Float16)acc[m][n][j];
            }
    } else {
        _Float16* dst = (mode == 0) ? qh : kh;
        const int ldd = (mode == 0) ? NQc : NKVc;
        const float qs = (mode == 0) ? 0.125f : 1.0f;
        const int colb = col0 + wc * 64;
#pragma unroll
        for (int m = 0; m < 2; ++m)
#pragma unroll
            for (int j = 0; j < 4; ++j) {
                const int row = row0 + wr * 32 + m * 16 + fq * 4 + j;
                const int s   = row & (Sseq - 1);
                const float c0 = cosT[s * HDm + fr],      s0 = sinT[s * HDm + fr];
                const float c1 = cosT[s * HDm + 16 + fr], s1 = sinT[s * HDm + 16 + fr];
                const float o0 = acc[m][0][j], o1 = acc[m][1][j];
                const float o2 = acc[m][2][j], o3 = acc[m][3][j];
                _Float16* bp = dst + (size_t)row * ldd + colb;
                bp[fr]      = (_Float16)((o0 * c0 - o2 * s0) * qs);
                bp[16 + fr] = (_Float16)((o1 * c1 - o3 * s1) * qs);
                bp[32 + fr] = (_Float16)((o2 * c0 + o0 * s0) * qs);
                bp[48 + fr] = (_Float16)((o3 * c1 + o1 * s1) * qs);
            }
    }
}

// ---------------------------------------------------------------------------
// Output projection: BM=64 x BN=128 fp16-split, fp32 C. grid 16 x 32.
// ---------------------------------------------------------------------------
__global__ __launch_bounds__(256)
void gemm_out2(const _Float16* __restrict__ aohi, const _Float16* __restrict__ aolo,
               const _Float16* __restrict__ woT, float* __restrict__ C)
{
    __shared__ _Float16 sAhi[64 * 32];
    __shared__ _Float16 sAlo[64 * 32];
    __shared__ _Float16 sB[128 * 32];

    const int row0 = blockIdx.y * 64;
    const int col0 = blockIdx.x * 128;

    f32x4 acc[2][4];
#pragma unroll
    for (int m = 0; m < 2; ++m)
#pragma unroll
        for (int n = 0; n < 4; ++n)
            acc[m][n] = (f32x4){0.f, 0.f, 0.f, 0.f};

    gemm2_loop64(aohi, aolo, woT, NQc, row0, col0, sAhi, sAlo, sB, acc);

    const int lane = threadIdx.x & 63;
    const int wid  = threadIdx.x >> 6;
    const int wr   = wid >> 1, wc = wid & 1;
    const int fr   = lane & 15, fq = lane >> 4;
#pragma unroll
    for (int m = 0; m < 2; ++m)
#pragma unroll
        for (int j = 0; j < 4; ++j) {
            float* cp = C + (size_t)(row0 + wr * 32 + m * 16 + fq * 4 + j) * Ddim
                          + col0 + wc * 64 + fr;
#pragma unroll
            for (int n = 0; n < 4; ++n) cp[n * 16] = acc[m][n][j];
        }
}

// ---------------------------------------------------------------------------
// MFMA flash attention, fp16 inputs / fp32 softmax+accum, causal, GQA.
// Q read directly as fp16 (RoPE'd + pre-scaled). K [kcol][d], V^T [d][k] in
// LDS, XOR-swizzled. P via per-wave LDS (wave-local). Writes ao fp16 hi/lo
// directly (feeds gemm_out2; deletes the separate conv pass).
// ---------------------------------------------------------------------------
__global__ __launch_bounds__(256)
void flash_mfma(const _Float16* __restrict__ Qh, const _Float16* __restrict__ Kh,
                const _Float16* __restrict__ Vt,
                _Float16* __restrict__ aohi, _Float16* __restrict__ aolo,
                const int* __restrict__ spp)
{
    __shared__ _Float16 Ks[64 * 64];
    __shared__ _Float16 Vs[64 * 64];
    __shared__ _Float16 Ps[4][16 * 64];

    const int qb = blockIdx.x;
    const int h  = blockIdx.y;
    const int b  = blockIdx.z;
    const int g  = h >> 2;
    const int sp = *spp;
    const int t  = threadIdx.x;
    const int lane = t & 63;
    const int wid  = t >> 6;
    const int fr = lane & 15;
    const int fq = lane >> 4;

    // Q A-fragments, direct fp16 load
    f16x8 qf[2];
    {
        const _Float16* qp = Qh + (size_t)(b * Sseq + qb * 64 + wid * 16 + fr) * NQc + h * HDm;
#pragma unroll
        for (int c = 0; c < 2; ++c)
            qf[c] = *reinterpret_cast<const f16x8*>(qp + c * 32 + fq * 8);
    }

    f32x4 accO[4];
    float m_i[4], l_i[4];
#pragma unroll
    for (int n = 0; n < 4; ++n) accO[n] = (f32x4){0.f, 0.f, 0.f, 0.f};
#pragma unroll
    for (int j = 0; j < 4; ++j) { m_i[j] = -1e30f; l_i[j] = 0.f; }

    const int nkb = min(Sseq >> 6, ((qb * 64 + 63 + sp) >> 6) + 1);

    for (int kb = 0; kb < nkb; ++kb) {
        __syncthreads();
#pragma unroll
        for (int c2 = 0; c2 < 2; ++c2) {
            const int idx = t + c2 * 256;
            const int r  = idx >> 3;
            const int ch = idx & 7;
            const int sw = (ch ^ (r & 7)) << 3;
            const uint4 kv = *reinterpret_cast<const uint4*>(
                Kh + (size_t)(b * Sseq + kb * 64 + r) * NKVc + g * HDm + ch * 8);
            *reinterpret_cast<uint4*>(&Ks[r * 64 + sw]) = kv;
            const uint4 vv = *reinterpret_cast<const uint4*>(
                Vt + ((size_t)(b * Hkv + g) * HDm + r) * Sseq + kb * 64 + ch * 8);
            *reinterpret_cast<uint4*>(&Vs[r * 64 + sw]) = vv;
        }
        __syncthreads();

        // S = Q K^T : acc col = kcol(n*16+fr), row = q(fq*4+j)
        f32x4 accS[4];
#pragma unroll
        for (int n = 0; n < 4; ++n) accS[n] = (f32x4){0.f, 0.f, 0.f, 0.f};
#pragma unroll
        for (int n = 0; n < 4; ++n)
#pragma unroll
            for (int c = 0; c < 2; ++c) {
                const int r  = n * 16 + fr;
                const int cc = c * 4 + fq;
                const f16x8 kf = *reinterpret_cast<const f16x8*>(
                    &Ks[r * 64 + ((cc ^ (r & 7)) << 3)]);
                accS[n] = __builtin_amdgcn_mfma_f32_16x16x32_f16(qf[c], kf, accS[n], 0, 0, 0);
            }

        // Causal mask (diagonal block only)
        if (kb * 64 + 63 > qb * 64 + sp) {
            const int q0 = sp + qb * 64 + wid * 16 + fq * 4;
            const int k0 = kb * 64 + fr;
#pragma unroll
            for (int n = 0; n < 4; ++n)
#pragma unroll
                for (int j = 0; j < 4; ++j)
                    if (k0 + n * 16 > q0 + j) accS[n][j] = -1e30f;
        }

        // Online softmax (rows on (fq,j); reduce across 16 fr-lanes)
#pragma unroll
        for (int j = 0; j < 4; ++j) {
            float mx = fmaxf(fmaxf(accS[0][j], accS[1][j]), fmaxf(accS[2][j], accS[3][j]));
#pragma unroll
            for (int msk = 1; msk < 16; msk <<= 1)
                mx = fmaxf(mx, __shfl_xor(mx, msk));
            const float mnew = fmaxf(m_i[j], mx);
            const float corr = __expf(m_i[j] - mnew);
            m_i[j] = mnew;
            float rs = 0.f;
#pragma unroll
            for (int n = 0; n < 4; ++n) {
                const float p = __expf(accS[n][j] - mnew);
                accS[n][j] = p;
                rs += p;
            }
#pragma unroll
            for (int msk = 1; msk < 16; msk <<= 1)
                rs += __shfl_xor(rs, msk);
            l_i[j] = l_i[j] * corr + rs;
#pragma unroll
            for (int n = 0; n < 4; ++n) accO[n][j] *= corr;
            const int prow = fq * 4 + j;
#pragma unroll
            for (int n = 0; n < 4; ++n) {
                const int col = n * 16 + fr;
                Ps[wid][prow * 64 + (((col >> 3) ^ (prow & 7)) << 3) + (col & 7)] =
                    (_Float16)accS[n][j];
            }
        }

        // P A-fragments (wave-local LDS, ordered by lgkmcnt — no barrier)
        f16x8 pa[2];
#pragma unroll
        for (int c = 0; c < 2; ++c) {
            const int cc = c * 4 + fq;
            pa[c] = *reinterpret_cast<const f16x8*>(
                &Ps[wid][fr * 64 + ((cc ^ (fr & 7)) << 3)]);
        }
        // O += P V : acc col = d(n*16+fr), row = q(fq*4+j)
#pragma unroll
        for (int n = 0; n < 4; ++n)
#pragma unroll
            for (int c = 0; c < 2; ++c) {
                const int r  = n * 16 + fr;
                const int cc = c * 4 + fq;
                const f16x8 vf = *reinterpret_cast<const f16x8*>(
                    &Vs[r * 64 + ((cc ^ (r & 7)) << 3)]);
                accO[n] = __builtin_amdgcn_mfma_f32_16x16x32_f16(pa[c], vf, accO[n], 0, 0, 0);
            }
    }

    // Epilogue: normalize, write ao fp16 hi/lo directly
#pragma unroll
    for (int j = 0; j < 4; ++j) {
        const float inv = 1.0f / l_i[j];
        const size_t rowg = (size_t)(b * Sseq + qb * 64 + wid * 16 + fq * 4 + j) * NQc;
#pragma unroll
        for (int n = 0; n < 4; ++n) {
            const float o = accO[n][j] * inv;
            const _Float16 hh = (_Float16)o;
            aohi[rowg + h * HDm + n * 16 + fr] = hh;
            aolo[rowg + h * HDm + n * 16 + fr] = (_Float16)(o - (float)hh);
        }
    }
}

// ---------------------------------------------------------------------------
// Launcher. Workspace (48 MB):
//  0..8 wqT16 | 8..10 wkT16 | 10..12 wvT16 | 12..20 woT16
//  20..28 xhi (later aohi) | 28..36 xlo (later aolo)
//  36..44 qh | 44..46 kh | 46..48 vT
// ---------------------------------------------------------------------------
extern "C" void kernel_launch(void* const* d_in, const int* in_sizes, int n_in,
                              void* d_out, int out_size, void* d_ws, size_t ws_size,
                              hipStream_t stream)
{
    const float* x    = (const float*)d_in[0];
    const float* wq   = (const float*)d_in[1];
    const float* wk   = (const float*)d_in[2];
    const float* wv   = (const float*)d_in[3];
    const float* wo   = (const float*)d_in[4];
    const float* cosT = (const float*)d_in[5];
    const float* sinT = (const float*)d_in[6];
    const int*   spp  = (const int*)d_in[7];
    float*       out  = (float*)d_out;

    char* w = (char*)d_ws;
    _Float16* wqT16 = (_Float16*)(w);
    _Float16* wkT16 = (_Float16*)(w + (8ull  << 20));
    _Float16* wvT16 = (_Float16*)(w + (10ull << 20));
    _Float16* woT16 = (_Float16*)(w + (12ull << 20));
    _Float16* xhi   = (_Float16*)(w + (20ull << 20));
    _Float16* xlo   = (_Float16*)(w + (28ull << 20));
    _Float16* aohi  = (_Float16*)(w + (20ull << 20));  // alias xhi (dead post-QKV)
    _Float16* aolo  = (_Float16*)(w + (28ull << 20));  // alias xlo
    _Float16* qh    = (_Float16*)(w + (36ull << 20));
    _Float16* kh    = (_Float16*)(w + (44ull << 20));
    _Float16* vT    = (_Float16*)(w + (46ull << 20));

    // Input conversions
    conv_split16<<<2048, 256, 0, stream>>>(x, xhi, xlo);
    conv_w16t<<<10240, 256, 0, stream>>>(wq, wk, wv, wo, wqT16, wkT16, wvT16, woT16);

    // Fused QKV projection + RoPE + packing (q fp16, k fp16, vT fp16)
    gemm_qkv2<<<dim3(24, 32), 256, 0, stream>>>(xhi, xlo, wqT16, wkT16, wvT16,
                                                cosT, sinT, qh, kh, vT);

    // MFMA flash attention (writes ao fp16 hi/lo directly)
    flash_mfma<<<dim3(Sseq / 64, Hq, Bsz), 256, 0, stream>>>(qh, kh, vT, aohi, aolo, spp);

    // Output projection
    gemm_out2<<<dim3(16, 32), 256, 0, stream>>>(aohi, aolo, woT16, out);
}

// Round 11
// 264.787 us; speedup vs baseline: 5.0678x; 1.0547x over previous
//
#include <hip/hip_runtime.h>
#include <cstdint>
#include <cstddef>

// Problem constants
#define Bsz   2
#define Sseq  1024
#define Ddim  2048
#define Hq    32
#define Hkv   8
#define HDm   64
#define MROWS (Bsz * Sseq)   // 2048
#define NQc   (Hq * HDm)     // 2048
#define NKVc  (Hkv * HDm)    // 512

typedef __attribute__((ext_vector_type(8))) _Float16 f16x8;
typedef __attribute__((ext_vector_type(4))) float    f32x4;

// async global->LDS, 16B per lane; LDS dest is wave-uniform base + lane*16
__device__ __forceinline__ void gload_lds16(const void* g, void* s) {
    __builtin_amdgcn_global_load_lds(
        (const __attribute__((address_space(1))) void*)g,
        (__attribute__((address_space(3))) void*)s, 16, 0, 0);
}

// ---------------------------------------------------------------------------
// fp32 -> fp16 hi/lo split, same layout. One thread per 8 floats.
// ---------------------------------------------------------------------------
__global__ __launch_bounds__(256)
void conv_split16(const float* __restrict__ in, _Float16* __restrict__ hi,
                  _Float16* __restrict__ lo)
{
    const int i = blockIdx.x * 256 + threadIdx.x;
    const float4 v0 = reinterpret_cast<const float4*>(in)[i * 2];
    const float4 v1 = reinterpret_cast<const float4*>(in)[i * 2 + 1];
    const float a[8] = {v0.x, v0.y, v0.z, v0.w, v1.x, v1.y, v1.z, v1.w};
    f16x8 h, l;
#pragma unroll
    for (int j = 0; j < 8; ++j) {
        const _Float16 hh = (_Float16)a[j];
        h[j] = hh;
        l[j] = (_Float16)(a[j] - (float)hh);
    }
    *reinterpret_cast<f16x8*>(hi + (size_t)i * 8) = h;
    *reinterpret_cast<f16x8*>(lo + (size_t)i * 8) = l;
}

// ---------------------------------------------------------------------------
// All 4 weight matrices fp32 [R][C] -> single fp16 transposed [C][R].
// ---------------------------------------------------------------------------
__global__ __launch_bounds__(256)
void conv_w16t(const float* __restrict__ wq, const float* __restrict__ wk,
               const float* __restrict__ wv, const float* __restrict__ wo,
               _Float16* __restrict__ oq, _Float16* __restrict__ ok,
               _Float16* __restrict__ ov, _Float16* __restrict__ oo)
{
    __shared__ float tile[32][33];
    const int id = blockIdx.x;
    const float* src; _Float16* dst; int C, t;
    if (id < 4096)      { src = wq; dst = oq; C = 2048; t = id; }
    else if (id < 5120) { src = wk; dst = ok; C = 512;  t = id - 4096; }
    else if (id < 6144) { src = wv; dst = ov; C = 512;  t = id - 5120; }
    else                { src = wo; dst = oo; C = 2048; t = id - 6144; }
    const int R = 2048;
    const int ctiles = C >> 5;
    const int c0 = (t % ctiles) * 32, r0 = (t / ctiles) * 32;
    const int tx = threadIdx.x & 31, ty = threadIdx.x >> 5;
#pragma unroll
    for (int p = 0; p < 4; ++p) {
        const int r = ty + p * 8;
        tile[r][tx] = src[(size_t)(r0 + r) * C + c0 + tx];
    }
    __syncthreads();
#pragma unroll
    for (int p = 0; p < 4; ++p) {
        const int cc = ty + p * 8;
        dst[(size_t)(c0 + cc) * R + r0 + tx] = (_Float16)tile[tx][cc];
    }
}

// ---------------------------------------------------------------------------
// 2-MFMA fp16-split GEMM main loop, BM=64 x BN=128, BK=32, 4 waves (2x2).
// ---------------------------------------------------------------------------
__device__ __forceinline__
void gemm2_loop64(const _Float16* __restrict__ Ahi, const _Float16* __restrict__ Alo,
                  const _Float16* __restrict__ Bt, int Kdim, int row0, int col0,
                  _Float16* sAhi, _Float16* sAlo, _Float16* sB,
                  f32x4 (&acc)[2][4])
{
    const int t    = threadIdx.x;
    const int lane = t & 63;
    const int wid  = t >> 6;
    const int wr   = wid >> 1;
    const int wc   = wid & 1;
    const int fr   = lane & 15;
    const int kc   = (lane >> 4) * 8;
    const int srow = lane >> 2;           // staging row within 16-row segment
    const int scol = (lane & 3) * 8;      // staging col (8 fp16 = 16B)

    for (int k0 = 0; k0 < Kdim; k0 += 32) {
        __syncthreads();
        // A (64 rows): segment wid; B (128 rows): segments 2*wid, 2*wid+1
        {
            const size_t ga = (size_t)(row0 + wid * 16 + srow) * Kdim + k0 + scol;
            gload_lds16(Ahi + ga, (char*)sAhi + wid * 1024);
            gload_lds16(Alo + ga, (char*)sAlo + wid * 1024);
#pragma unroll
            for (int c = 0; c < 2; ++c) {
                const int seg = 2 * wid + c;
                const size_t gb = (size_t)(col0 + seg * 16 + srow) * Kdim + k0 + scol;
                gload_lds16(Bt + gb, (char*)sB + seg * 1024);
            }
        }
        __syncthreads();

        f16x8 ah[2], al[2], bb[4];
        const int ar = wr * 32 + fr;
        const int br = wc * 64 + fr;
#pragma unroll
        for (int m = 0; m < 2; ++m) {
            ah[m] = *reinterpret_cast<const f16x8*>(&sAhi[(ar + m * 16) * 32 + kc]);
            al[m] = *reinterpret_cast<const f16x8*>(&sAlo[(ar + m * 16) * 32 + kc]);
        }
#pragma unroll
        for (int n = 0; n < 4; ++n)
            bb[n] = *reinterpret_cast<const f16x8*>(&sB[(br + n * 16) * 32 + kc]);
#pragma unroll
        for (int m = 0; m < 2; ++m)
#pragma unroll
            for (int n = 0; n < 4; ++n) {
                acc[m][n] = __builtin_amdgcn_mfma_f32_16x16x32_f16(ah[m], bb[n], acc[m][n], 0, 0, 0);
                acc[m][n] = __builtin_amdgcn_mfma_f32_16x16x32_f16(al[m], bb[n], acc[m][n], 0, 0, 0);
            }
    }
}

// ---------------------------------------------------------------------------
// Fused QKV projection + RoPE epilogue + direct packing.
// q is pre-scaled by 0.125*log2(e) so flash can use exp2 directly.
// ---------------------------------------------------------------------------
__global__ __launch_bounds__(256)
void gemm_qkv2(const _Float16* __restrict__ xhi, const _Float16* __restrict__ xlo,
               const _Float16* __restrict__ wqT, const _Float16* __restrict__ wkT,
               const _Float16* __restrict__ wvT,
               const float* __restrict__ cosT, const float* __restrict__ sinT,
               _Float16* __restrict__ qh, _Float16* __restrict__ kh,
               _Float16* __restrict__ vT)
{
    __shared__ _Float16 sAhi[64 * 32];
    __shared__ _Float16 sAlo[64 * 32];
    __shared__ _Float16 sB[128 * 32];

    const int bx   = blockIdx.x;
    const int row0 = blockIdx.y * 64;
    const _Float16* Bt; int col0, mode;
    if (bx < 16)      { Bt = wqT; col0 = bx * 128;        mode = 0; }
    else if (bx < 20) { Bt = wkT; col0 = (bx - 16) * 128; mode = 1; }
    else              { Bt = wvT; col0 = (bx - 20) * 128; mode = 2; }

    f32x4 acc[2][4];
#pragma unroll
    for (int m = 0; m < 2; ++m)
#pragma unroll
        for (int n = 0; n < 4; ++n)
            acc[m][n] = (f32x4){0.f, 0.f, 0.f, 0.f};

    gemm2_loop64(xhi, xlo, Bt, Ddim, row0, col0, sAhi, sAlo, sB, acc);

    const int lane = threadIdx.x & 63;
    const int wid  = threadIdx.x >> 6;
    const int wr   = wid >> 1, wc = wid & 1;
    const int fr   = lane & 15, fq = lane >> 4;

    if (mode == 2) {
        // vT[(b*8+g)*64 + d][s], d = n*16+fr, g from wave's 64-col span
        const int gg = (col0 + wc * 64) >> 6;
#pragma unroll
        for (int m = 0; m < 2; ++m)
#pragma unroll
            for (int j = 0; j < 4; ++j) {
                const int row = row0 + wr * 32 + m * 16 + fq * 4 + j;
                const int b = row >> 10, s = row & (Sseq - 1);
#pragma unroll
                for (int n = 0; n < 4; ++n)
                    vT[(((size_t)((b * 8 + gg) * 64 + n * 16 + fr)) << 10) + s] =
                        (_Float16)acc[m][n][j];
            }
    } else {
        _Float16* dst = (mode == 0) ? qh : kh;
        const int ldd = (mode == 0) ? NQc : NKVc;
        // q scale folds 1/sqrt(64) and log2(e) for exp2-based softmax
        const float qs = (mode == 0) ? 0.125f * 1.4426950408889634f : 1.0f;
        const int colb = col0 + wc * 64;
#pragma unroll
        for (int m = 0; m < 2; ++m)
#pragma unroll
            for (int j = 0; j < 4; ++j) {
                const int row = row0 + wr * 32 + m * 16 + fq * 4 + j;
                const int s   = row & (Sseq - 1);
                const float c0 = cosT[s * HDm + fr],      s0 = sinT[s * HDm + fr];
                const float c1 = cosT[s * HDm + 16 + fr], s1 = sinT[s * HDm + 16 + fr];
                const float o0 = acc[m][0][j], o1 = acc[m][1][j];
                const float o2 = acc[m][2][j], o3 = acc[m][3][j];
                _Float16* bp = dst + (size_t)row * ldd + colb;
                bp[fr]      = (_Float16)((o0 * c0 - o2 * s0) * qs);
                bp[16 + fr] = (_Float16)((o1 * c1 - o3 * s1) * qs);
                bp[32 + fr] = (_Float16)((o2 * c0 + o0 * s0) * qs);
                bp[48 + fr] = (_Float16)((o3 * c1 + o1 * s1) * qs);
            }
    }
}

// ---------------------------------------------------------------------------
// Output projection: BM=64 x BN=128 fp16-split, fp32 C. grid 16 x 32.
// ---------------------------------------------------------------------------
__global__ __launch_bounds__(256)
void gemm_out2(const _Float16* __restrict__ aohi, const _Float16* __restrict__ aolo,
               const _Float16* __restrict__ woT, float* __restrict__ C)
{
    __shared__ _Float16 sAhi[64 * 32];
    __shared__ _Float16 sAlo[64 * 32];
    __shared__ _Float16 sB[128 * 32];

    const int row0 = blockIdx.y * 64;
    const int col0 = blockIdx.x * 128;

    f32x4 acc[2][4];
#pragma unroll
    for (int m = 0; m < 2; ++m)
#pragma unroll
        for (int n = 0; n < 4; ++n)
            acc[m][n] = (f32x4){0.f, 0.f, 0.f, 0.f};

    gemm2_loop64(aohi, aolo, woT, NQc, row0, col0, sAhi, sAlo, sB, acc);

    const int lane = threadIdx.x & 63;
    const int wid  = threadIdx.x >> 6;
    const int wr   = wid >> 1, wc = wid & 1;
    const int fr   = lane & 15, fq = lane >> 4;
#pragma unroll
    for (int m = 0; m < 2; ++m)
#pragma unroll
        for (int j = 0; j < 4; ++j) {
            float* cp = C + (size_t)(row0 + wr * 32 + m * 16 + fq * 4 + j) * Ddim
                          + col0 + wc * 64 + fr;
#pragma unroll
            for (int n = 0; n < 4; ++n) cp[n * 16] = acc[m][n][j];
        }
}

// ---------------------------------------------------------------------------
// Swapped-QK MFMA flash attention: compute S^T = mfma(K, Q) so each lane owns
// ONE q-row (q = lane&15) -> softmax reduce = 16 in-lane ops + 2 shuffles
// (vs 32 butterfly shuffles), P-pack = 4 ds_write_b64 (vs 16 b16).
// QBLK=128, 8 waves (512 thr); K [kcol][d], V^T [d][k] LDS tiles XOR-swizzled.
// Q (pre-scaled by 0.125*log2e) is read as B-fragment directly from registers.
// accO comes out in standard layout (rows q on (fq,j)); corr/1/l broadcast via
// 4 shuffles. Writes ao fp16 hi/lo. Heavy blocks (qb high) dispatched first.
// ---------------------------------------------------------------------------
__global__ __launch_bounds__(512)
void flash_mfma(const _Float16* __restrict__ Qh, const _Float16* __restrict__ Kh,
                const _Float16* __restrict__ Vt,
                _Float16* __restrict__ aohi, _Float16* __restrict__ aolo,
                const int* __restrict__ spp)
{
    __shared__ _Float16 Ks[64 * 64];
    __shared__ _Float16 Vs[64 * 64];
    __shared__ _Float16 Ps[8][16 * 64];

    const int qb = (Sseq / 128 - 1) - blockIdx.x;   // heavy blocks first
    const int h  = blockIdx.y;
    const int b  = blockIdx.z;
    const int g  = h >> 2;
    const int sp = *spp;
    const int t  = threadIdx.x;
    const int lane = t & 63;
    const int wid  = t >> 6;        // 0..7; wave q-rows = qb*128 + wid*16 + [0,16)
    const int fr = lane & 15;       // this lane's q-row within the wave
    const int fq = lane >> 4;       // quarter (k-chunk index)

    // Q as B-fragment: lane holds Q[q = wid*16+fr][d = c*32 + fq*8 + i]
    f16x8 qf[2];
    {
        const _Float16* qp = Qh + (size_t)(b * Sseq + qb * 128 + wid * 16 + fr) * NQc + h * HDm;
        qf[0] = *reinterpret_cast<const f16x8*>(qp + fq * 8);
        qf[1] = *reinterpret_cast<const f16x8*>(qp + 32 + fq * 8);
    }

    f32x4 accO[4];                  // O[q = fq*4+j][d = n*16+fr]
#pragma unroll
    for (int n = 0; n < 4; ++n) accO[n] = (f32x4){0.f, 0.f, 0.f, 0.f};
    float m_i = -1e30f, l_i = 0.f;  // state for row q=fr (replicated across fq)

    char* const pbase = (char*)Ps[wid] + fr * 128;
    const int swz = (fr & 7) << 4;

    const int nkb = min(Sseq >> 6, ((qb * 128 + 127 + sp) >> 6) + 1);

    for (int kb = 0; kb < nkb; ++kb) {
        __syncthreads();            // all 8 waves done with prev Ks/Vs
        {   // stage K [kcol][d] and V^T [d][k] tiles (8 KB each), 512 thr x 16B
            const int r  = t >> 3;
            const int ch = t & 7;
            const int sw = (ch ^ (r & 7)) << 3;
            *reinterpret_cast<uint4*>(&Ks[r * 64 + sw]) =
                *reinterpret_cast<const uint4*>(
                    Kh + (size_t)(b * Sseq + kb * 64 + r) * NKVc + g * HDm + ch * 8);
            *reinterpret_cast<uint4*>(&Vs[r * 64 + sw]) =
                *reinterpret_cast<const uint4*>(
                    Vt + ((size_t)(b * Hkv + g) * HDm + r) * Sseq + kb * 64 + ch * 8);
        }
        __syncthreads();

        // S^T = K Q^T : acc rows k = n*16+fq*4+j, col q = fr
        f32x4 accS[4];
#pragma unroll
        for (int n = 0; n < 4; ++n) accS[n] = (f32x4){0.f, 0.f, 0.f, 0.f};
#pragma unroll
        for (int n = 0; n < 4; ++n)
#pragma unroll
            for (int c = 0; c < 2; ++c) {
                const int r  = n * 16 + fr;
                const int cc = c * 4 + fq;
                const f16x8 kf = *reinterpret_cast<const f16x8*>(
                    &Ks[r * 64 + ((cc ^ (r & 7)) << 3)]);
                accS[n] = __builtin_amdgcn_mfma_f32_16x16x32_f16(kf, qf[c], accS[n], 0, 0, 0);
            }

        // Causal mask (diagonal region only): k_global > q_global ?
        if (kb * 64 + 63 > qb * 128 + wid * 16 + sp) {
            const int q0 = sp + qb * 128 + wid * 16 + fr;
            const int k0 = kb * 64 + fq * 4;
#pragma unroll
            for (int n = 0; n < 4; ++n)
#pragma unroll
                for (int j = 0; j < 4; ++j)
                    if (k0 + n * 16 + j > q0) accS[n][j] = -1e30f;
        }

        // Online softmax for row q=fr (scores already in log2e units)
        float mx = -1e30f;
#pragma unroll
        for (int n = 0; n < 4; ++n)
#pragma unroll
            for (int j = 0; j < 4; ++j) mx = fmaxf(mx, accS[n][j]);
        mx = fmaxf(mx, __shfl_xor(mx, 16));
        mx = fmaxf(mx, __shfl_xor(mx, 32));
        const float mnew = fmaxf(m_i, mx);
        const float corr = exp2f(m_i - mnew);
        m_i = mnew;
        float rs = 0.f;
#pragma unroll
        for (int n = 0; n < 4; ++n)
#pragma unroll
            for (int j = 0; j < 4; ++j) {
                const float p = exp2f(accS[n][j] - mnew);
                accS[n][j] = p;
                rs += p;
            }
        rs += __shfl_xor(rs, 16);
        rs += __shfl_xor(rs, 32);
        l_i = l_i * corr + rs;

        // Broadcast corr to accO's row layout (rows q = fq*4+j) and rescale
        {
            float cj[4];
#pragma unroll
            for (int j = 0; j < 4; ++j)
                cj[j] = __shfl(corr, (lane & 48) + fq * 4 + j);
#pragma unroll
            for (int n = 0; n < 4; ++n)
#pragma unroll
                for (int j = 0; j < 4; ++j) accO[n][j] *= cj[j];
        }

        // Pack P row into per-wave LDS (4 x ds_write_b64), then read A-frags
#pragma unroll
        for (int n = 0; n < 4; ++n) {
            union { _Float16 hh[4]; uint2 u; } pk;
#pragma unroll
            for (int j = 0; j < 4; ++j) pk.hh[j] = (_Float16)accS[n][j];
            *reinterpret_cast<uint2*>(pbase + ((n * 32 + fq * 8) ^ swz)) = pk.u;
        }
        f16x8 pa[2];
#pragma unroll
        for (int c = 0; c < 2; ++c)
            pa[c] = *reinterpret_cast<const f16x8*>(pbase + ((c * 64 + fq * 16) ^ swz));

        // O += P V : acc col d = n*16+fr, row q = fq*4+j
#pragma unroll
        for (int n = 0; n < 4; ++n)
#pragma unroll
            for (int c = 0; c < 2; ++c) {
                const int r  = n * 16 + fr;
                const int cc = c * 4 + fq;
                const f16x8 vf = *reinterpret_cast<const f16x8*>(
                    &Vs[r * 64 + ((cc ^ (r & 7)) << 3)]);
                accO[n] = __builtin_amdgcn_mfma_f32_16x16x32_f16(pa[c], vf, accO[n], 0, 0, 0);
            }
    }

    // Epilogue: broadcast 1/l to accO rows, write ao fp16 hi/lo
    const float invl = 1.0f / l_i;
    float iv[4];
#pragma unroll
    for (int j = 0; j < 4; ++j)
        iv[j] = __shfl(invl, (lane & 48) + fq * 4 + j);
#pragma unroll
    for (int j = 0; j < 4; ++j) {
        const size_t rowg = (size_t)(b * Sseq + qb * 128 + wid * 16 + fq * 4 + j) * NQc;
#pragma unroll
        for (int n = 0; n < 4; ++n) {
            const float o = accO[n][j] * iv[j];
            const _Float16 hh = (_Float16)o;
            aohi[rowg + h * HDm + n * 16 + fr] = hh;
            aolo[rowg + h * HDm + n * 16 + fr] = (_Float16)(o - (float)hh);
        }
    }
}

// ---------------------------------------------------------------------------
// Launcher. Workspace (48 MB):
//  0..8 wqT16 | 8..10 wkT16 | 10..12 wvT16 | 12..20 woT16
//  20..28 xhi (later aohi) | 28..36 xlo (later aolo)
//  36..44 qh | 44..46 kh | 46..48 vT
// ---------------------------------------------------------------------------
extern "C" void kernel_launch(void* const* d_in, const int* in_sizes, int n_in,
                              void* d_out, int out_size, void* d_ws, size_t ws_size,
                              hipStream_t stream)
{
    const float* x    = (const float*)d_in[0];
    const float* wq   = (const float*)d_in[1];
    const float* wk   = (const float*)d_in[2];
    const float* wv   = (const float*)d_in[3];
    const float* wo   = (const float*)d_in[4];
    const float* cosT = (const float*)d_in[5];
    const float* sinT = (const float*)d_in[6];
    const int*   spp  = (const int*)d_in[7];
    float*       out  = (float*)d_out;

    char* w = (char*)d_ws;
    _Float16* wqT16 = (_Float16*)(w);
    _Float16* wkT16 = (_Float16*)(w + (8ull  << 20));
    _Float16* wvT16 = (_Float16*)(w + (10ull << 20));
    _Float16* woT16 = (_Float16*)(w + (12ull << 20));
    _Float16* xhi   = (_Float16*)(w + (20ull << 20));
    _Float16* xlo   = (_Float16*)(w + (28ull << 20));
    _Float16* aohi  = (_Float16*)(w + (20ull << 20));  // alias xhi (dead post-QKV)
    _Float16* aolo  = (_Float16*)(w + (28ull << 20));  // alias xlo
    _Float16* qh    = (_Float16*)(w + (36ull << 20));
    _Float16* kh    = (_Float16*)(w + (44ull << 20));
    _Float16* vT    = (_Float16*)(w + (46ull << 20));

    // Input conversions
    conv_split16<<<2048, 256, 0, stream>>>(x, xhi, xlo);
    conv_w16t<<<10240, 256, 0, stream>>>(wq, wk, wv, wo, wqT16, wkT16, wvT16, woT16);

    // Fused QKV projection + RoPE + packing (q fp16 pre-scaled, k fp16, vT fp16)
    gemm_qkv2<<<dim3(24, 32), 256, 0, stream>>>(xhi, xlo, wqT16, wkT16, wvT16,
                                                cosT, sinT, qh, kh, vT);

    // Swapped-QK MFMA flash attention (writes ao fp16 hi/lo directly)
    flash_mfma<<<dim3(Sseq / 128, Hq, Bsz), 512, 0, stream>>>(qh, kh, vT, aohi, aolo, spp);

    // Output projection
    gemm_out2<<<dim3(16, 32), 256, 0, stream>>>(aohi, aolo, woT16, out);
}

// Round 12
// 223.864 us; speedup vs baseline: 5.9942x; 1.1828x over previous
//
#include <hip/hip_runtime.h>
#include <cstdint>
#include <cstddef>

// Problem constants
#define Bsz   2
#define Sseq  1024
#define Ddim  2048
#define Hq    32
#define Hkv   8
#define HDm   64
#define MROWS (Bsz * Sseq)   // 2048
#define NQc   (Hq * HDm)     // 2048
#define NKVc  (Hkv * HDm)    // 512

typedef __attribute__((ext_vector_type(8))) _Float16 f16x8;
typedef __attribute__((ext_vector_type(4))) float    f32x4;

// async global->LDS, 16B per lane; LDS dest is wave-uniform base + lane*16
__device__ __forceinline__ void gload_lds16(const void* g, void* s) {
    __builtin_amdgcn_global_load_lds(
        (const __attribute__((address_space(1))) void*)g,
        (__attribute__((address_space(3))) void*)s, 16, 0, 0);
}

// ---------------------------------------------------------------------------
// fp32 -> fp16 (single), same layout. One thread per 8 floats.
// ---------------------------------------------------------------------------
__global__ __launch_bounds__(256)
void conv_x16(const float* __restrict__ in, _Float16* __restrict__ out)
{
    const int i = blockIdx.x * 256 + threadIdx.x;
    const float4 v0 = reinterpret_cast<const float4*>(in)[i * 2];
    const float4 v1 = reinterpret_cast<const float4*>(in)[i * 2 + 1];
    f16x8 h;
    h[0] = (_Float16)v0.x; h[1] = (_Float16)v0.y; h[2] = (_Float16)v0.z; h[3] = (_Float16)v0.w;
    h[4] = (_Float16)v1.x; h[5] = (_Float16)v1.y; h[6] = (_Float16)v1.z; h[7] = (_Float16)v1.w;
    *reinterpret_cast<f16x8*>(out + (size_t)i * 8) = h;
}

// ---------------------------------------------------------------------------
// All 4 weight matrices fp32 [R][C] -> single fp16 transposed [C][R].
// ---------------------------------------------------------------------------
__global__ __launch_bounds__(256)
void conv_w16t(const float* __restrict__ wq, const float* __restrict__ wk,
               const float* __restrict__ wv, const float* __restrict__ wo,
               _Float16* __restrict__ oq, _Float16* __restrict__ ok,
               _Float16* __restrict__ ov, _Float16* __restrict__ oo)
{
    __shared__ float tile[32][33];
    const int id = blockIdx.x;
    const float* src; _Float16* dst; int C, t;
    if (id < 4096)      { src = wq; dst = oq; C = 2048; t = id; }
    else if (id < 5120) { src = wk; dst = ok; C = 512;  t = id - 4096; }
    else if (id < 6144) { src = wv; dst = ov; C = 512;  t = id - 5120; }
    else                { src = wo; dst = oo; C = 2048; t = id - 6144; }
    const int R = 2048;
    const int ctiles = C >> 5;
    const int c0 = (t % ctiles) * 32, r0 = (t / ctiles) * 32;
    const int tx = threadIdx.x & 31, ty = threadIdx.x >> 5;
#pragma unroll
    for (int p = 0; p < 4; ++p) {
        const int r = ty + p * 8;
        tile[r][tx] = src[(size_t)(r0 + r) * C + c0 + tx];
    }
    __syncthreads();
#pragma unroll
    for (int p = 0; p < 4; ++p) {
        const int cc = ty + p * 8;
        dst[(size_t)(c0 + cc) * R + r0 + tx] = (_Float16)tile[tx][cc];
    }
}

// ---------------------------------------------------------------------------
// Single-fp16 GEMM main loop, BM=64 x BN=128, BK=32, 4 waves (2x2).
// Per k-step per thread: 3 gload_lds + 6 ds_read_b128 + 8 MFMA.
// ---------------------------------------------------------------------------
__device__ __forceinline__
void gemm1_loop64(const _Float16* __restrict__ A, const _Float16* __restrict__ Bt,
                  int Kdim, int row0, int col0,
                  _Float16* sA, _Float16* sB, f32x4 (&acc)[2][4])
{
    const int t    = threadIdx.x;
    const int lane = t & 63;
    const int wid  = t >> 6;
    const int wr   = wid >> 1;
    const int wc   = wid & 1;
    const int fr   = lane & 15;
    const int kc   = (lane >> 4) * 8;
    const int srow = lane >> 2;           // staging row within 16-row segment
    const int scol = (lane & 3) * 8;      // staging col (8 fp16 = 16B)

    for (int k0 = 0; k0 < Kdim; k0 += 32) {
        __syncthreads();
        // A (64 rows): segment wid; B (128 rows): segments 2*wid, 2*wid+1
        {
            const size_t ga = (size_t)(row0 + wid * 16 + srow) * Kdim + k0 + scol;
            gload_lds16(A + ga, (char*)sA + wid * 1024);
#pragma unroll
            for (int c = 0; c < 2; ++c) {
                const int seg = 2 * wid + c;
                const size_t gb = (size_t)(col0 + seg * 16 + srow) * Kdim + k0 + scol;
                gload_lds16(Bt + gb, (char*)sB + seg * 1024);
            }
        }
        __syncthreads();

        f16x8 aa[2], bb[4];
        const int ar = wr * 32 + fr;
        const int br = wc * 64 + fr;
#pragma unroll
        for (int m = 0; m < 2; ++m)
            aa[m] = *reinterpret_cast<const f16x8*>(&sA[(ar + m * 16) * 32 + kc]);
#pragma unroll
        for (int n = 0; n < 4; ++n)
            bb[n] = *reinterpret_cast<const f16x8*>(&sB[(br + n * 16) * 32 + kc]);
#pragma unroll
        for (int m = 0; m < 2; ++m)
#pragma unroll
            for (int n = 0; n < 4; ++n)
                acc[m][n] = __builtin_amdgcn_mfma_f32_16x16x32_f16(aa[m], bb[n], acc[m][n], 0, 0, 0);
    }
}

// ---------------------------------------------------------------------------
// Fused QKV projection + RoPE epilogue + direct packing (single-fp16 A).
// q is pre-scaled by 0.125*log2(e) so flash can use exp2 directly.
// ---------------------------------------------------------------------------
__global__ __launch_bounds__(256)
void gemm_qkv2(const _Float16* __restrict__ xh,
               const _Float16* __restrict__ wqT, const _Float16* __restrict__ wkT,
               const _Float16* __restrict__ wvT,
               const float* __restrict__ cosT, const float* __restrict__ sinT,
               _Float16* __restrict__ qh, _Float16* __restrict__ kh,
               _Float16* __restrict__ vT)
{
    __shared__ _Float16 sA[64 * 32];
    __shared__ _Float16 sB[128 * 32];

    const int bx   = blockIdx.x;
    const int row0 = blockIdx.y * 64;
    const _Float16* Bt; int col0, mode;
    if (bx < 16)      { Bt = wqT; col0 = bx * 128;        mode = 0; }
    else if (bx < 20) { Bt = wkT; col0 = (bx - 16) * 128; mode = 1; }
    else              { Bt = wvT; col0 = (bx - 20) * 128; mode = 2; }

    f32x4 acc[2][4];
#pragma unroll
    for (int m = 0; m < 2; ++m)
#pragma unroll
        for (int n = 0; n < 4; ++n)
            acc[m][n] = (f32x4){0.f, 0.f, 0.f, 0.f};

    gemm1_loop64(xh, Bt, Ddim, row0, col0, sA, sB, acc);

    const int lane = threadIdx.x & 63;
    const int wid  = threadIdx.x >> 6;
    const int wr   = wid >> 1, wc = wid & 1;
    const int fr   = lane & 15, fq = lane >> 4;

    if (mode == 2) {
        // vT[(b*8+g)*64 + d][s], d = n*16+fr, g from wave's 64-col span
        const int gg = (col0 + wc * 64) >> 6;
#pragma unroll
        for (int m = 0; m < 2; ++m)
#pragma unroll
            for (int j = 0; j < 4; ++j) {
                const int row = row0 + wr * 32 + m * 16 + fq * 4 + j;
                const int b = row >> 10, s = row & (Sseq - 1);
#pragma unroll
                for (int n = 0; n < 4; ++n)
                    vT[(((size_t)((b * 8 + gg) * 64 + n * 16 + fr)) << 10) + s] =
                        (_Float16)acc[m][n][j];
            }
    } else {
        _Float16* dst = (mode == 0) ? qh : kh;
        const int ldd = (mode == 0) ? NQc : NKVc;
        // q scale folds 1/sqrt(64) and log2(e) for exp2-based softmax
        const float qs = (mode == 0) ? 0.125f * 1.4426950408889634f : 1.0f;
        const int colb = col0 + wc * 64;
#pragma unroll
        for (int m = 0; m < 2; ++m)
#pragma unroll
            for (int j = 0; j < 4; ++j) {
                const int row = row0 + wr * 32 + m * 16 + fq * 4 + j;
                const int s   = row & (Sseq - 1);
                const float c0 = cosT[s * HDm + fr],      s0 = sinT[s * HDm + fr];
                const float c1 = cosT[s * HDm + 16 + fr], s1 = sinT[s * HDm + 16 + fr];
                const float o0 = acc[m][0][j], o1 = acc[m][1][j];
                const float o2 = acc[m][2][j], o3 = acc[m][3][j];
                _Float16* bp = dst + (size_t)row * ldd + colb;
                bp[fr]      = (_Float16)((o0 * c0 - o2 * s0) * qs);
                bp[16 + fr] = (_Float16)((o1 * c1 - o3 * s1) * qs);
                bp[32 + fr] = (_Float16)((o2 * c0 + o0 * s0) * qs);
                bp[48 + fr] = (_Float16)((o3 * c1 + o1 * s1) * qs);
            }
    }
}

// ---------------------------------------------------------------------------
// Output projection: BM=64 x BN=128 single-fp16, fp32 C. grid 16 x 32.
// ---------------------------------------------------------------------------
__global__ __launch_bounds__(256)
void gemm_out2(const _Float16* __restrict__ ao16,
               const _Float16* __restrict__ woT, float* __restrict__ C)
{
    __shared__ _Float16 sA[64 * 32];
    __shared__ _Float16 sB[128 * 32];

    const int row0 = blockIdx.y * 64;
    const int col0 = blockIdx.x * 128;

    f32x4 acc[2][4];
#pragma unroll
    for (int m = 0; m < 2; ++m)
#pragma unroll
        for (int n = 0; n < 4; ++n)
            acc[m][n] = (f32x4){0.f, 0.f, 0.f, 0.f};

    gemm1_loop64(ao16, woT, NQc, row0, col0, sA, sB, acc);

    const int lane = threadIdx.x & 63;
    const int wid  = threadIdx.x >> 6;
    const int wr   = wid >> 1, wc = wid & 1;
    const int fr   = lane & 15, fq = lane >> 4;
#pragma unroll
    for (int m = 0; m < 2; ++m)
#pragma unroll
        for (int j = 0; j < 4; ++j) {
            float* cp = C + (size_t)(row0 + wr * 32 + m * 16 + fq * 4 + j) * Ddim
                          + col0 + wc * 64 + fr;
#pragma unroll
            for (int n = 0; n < 4; ++n) cp[n * 16] = acc[m][n][j];
        }
}

// ---------------------------------------------------------------------------
// Swapped-QK MFMA flash attention + T14 async staging.
// S^T = mfma(K, Q): each lane owns ONE q-row (q = lane&15); softmax reduce =
// 2 shuffles; P-pack = 4 ds_write_b64. QBLK=128, 8 waves (512 thr).
// K/V staged via register double-buffer: next tile's global loads issue
// right after this tile's LDS write; barriers are raw s_barrier preceded by
// lgkmcnt(0)-only waits so the in-flight global loads are NOT drained
// (avoids the vmcnt(0) barrier-drain stall). Writes ao single fp16.
// ---------------------------------------------------------------------------
__global__ __launch_bounds__(512)
void flash_mfma(const _Float16* __restrict__ Qh, const _Float16* __restrict__ Kh,
                const _Float16* __restrict__ Vt, _Float16* __restrict__ ao16,
                const int* __restrict__ spp)
{
    __shared__ _Float16 Ks[64 * 64];
    __shared__ _Float16 Vs[64 * 64];
    __shared__ _Float16 Ps[8][16 * 64];

    const int qb = (Sseq / 128 - 1) - blockIdx.x;   // heavy blocks first
    const int h  = blockIdx.y;
    const int b  = blockIdx.z;
    const int g  = h >> 2;
    const int sp = *spp;
    const int t  = threadIdx.x;
    const int lane = t & 63;
    const int wid  = t >> 6;        // 0..7; wave q-rows = qb*128 + wid*16 + [0,16)
    const int fr = lane & 15;       // this lane's q-row within the wave
    const int fq = lane >> 4;       // quarter (k-chunk index)

    // Q as B-fragment: lane holds Q[q = wid*16+fr][d = c*32 + fq*8 + i]
    f16x8 qf[2];
    {
        const _Float16* qp = Qh + (size_t)(b * Sseq + qb * 128 + wid * 16 + fr) * NQc + h * HDm;
        qf[0] = *reinterpret_cast<const f16x8*>(qp + fq * 8);
        qf[1] = *reinterpret_cast<const f16x8*>(qp + 32 + fq * 8);
    }

    f32x4 accO[4];                  // O[q = fq*4+j][d = n*16+fr]
#pragma unroll
    for (int n = 0; n < 4; ++n) accO[n] = (f32x4){0.f, 0.f, 0.f, 0.f};
    float m_i = -1e30f, l_i = 0.f;  // state for row q=fr (replicated across fq)

    char* const pbase = (char*)Ps[wid] + fr * 128;
    const int swz = (fr & 7) << 4;

    // Staging geometry (512 thr x 16B covers one 64x64 fp16 tile per buffer)
    const int sr  = t >> 3;
    const int sch = t & 7;
    const int ssw = (sch ^ (sr & 7)) << 3;
    const _Float16* kbase = Kh + (size_t)(b * Sseq + sr) * NKVc + g * HDm + sch * 8;
    const _Float16* vbase = Vt + ((size_t)(b * Hkv + g) * HDm + sr) * Sseq + sch * 8;

    const int nkb = min(Sseq >> 6, ((qb * 128 + 127 + sp) >> 6) + 1);

    // Preload tile 0 into registers
    uint4 kreg = *reinterpret_cast<const uint4*>(kbase);
    uint4 vreg = *reinterpret_cast<const uint4*>(vbase);

    for (int kb = 0; kb < nkb; ++kb) {
        // Barrier 1: all waves done reading prev Ks/Vs (LDS ops only; leave
        // global loads in flight).
        asm volatile("s_waitcnt lgkmcnt(0)" ::: "memory");
        __builtin_amdgcn_s_barrier();

        *reinterpret_cast<uint4*>(&Ks[sr * 64 + ssw]) = kreg;
        *reinterpret_cast<uint4*>(&Vs[sr * 64 + ssw]) = vreg;

        // Issue next tile's global loads now; latency hides under compute.
        if (kb + 1 < nkb) {
            kreg = *reinterpret_cast<const uint4*>(kbase + (size_t)(kb + 1) * 64 * NKVc);
            vreg = *reinterpret_cast<const uint4*>(vbase + (kb + 1) * 64);
        }

        // Barrier 2: ds_writes visible; do NOT drain vmcnt.
        asm volatile("s_waitcnt lgkmcnt(0)" ::: "memory");
        __builtin_amdgcn_s_barrier();

        // S^T = K Q^T : acc rows k = n*16+fq*4+j, col q = fr
        f32x4 accS[4];
#pragma unroll
        for (int n = 0; n < 4; ++n) accS[n] = (f32x4){0.f, 0.f, 0.f, 0.f};
#pragma unroll
        for (int n = 0; n < 4; ++n)
#pragma unroll
            for (int c = 0; c < 2; ++c) {
                const int r  = n * 16 + fr;
                const int cc = c * 4 + fq;
                const f16x8 kf = *reinterpret_cast<const f16x8*>(
                    &Ks[r * 64 + ((cc ^ (r & 7)) << 3)]);
                accS[n] = __builtin_amdgcn_mfma_f32_16x16x32_f16(kf, qf[c], accS[n], 0, 0, 0);
            }

        // Causal mask (diagonal region only): k_global > q_global ?
        if (kb * 64 + 63 > qb * 128 + wid * 16 + sp) {
            const int q0 = sp + qb * 128 + wid * 16 + fr;
            const int k0 = kb * 64 + fq * 4;
#pragma unroll
            for (int n = 0; n < 4; ++n)
#pragma unroll
                for (int j = 0; j < 4; ++j)
                    if (k0 + n * 16 + j > q0) accS[n][j] = -1e30f;
        }

        // Online softmax for row q=fr (scores already in log2e units)
        float mx = -1e30f;
#pragma unroll
        for (int n = 0; n < 4; ++n)
#pragma unroll
            for (int j = 0; j < 4; ++j) mx = fmaxf(mx, accS[n][j]);
        mx = fmaxf(mx, __shfl_xor(mx, 16));
        mx = fmaxf(mx, __shfl_xor(mx, 32));
        const float mnew = fmaxf(m_i, mx);
        const float corr = exp2f(m_i - mnew);
        m_i = mnew;
        float rs = 0.f;
#pragma unroll
        for (int n = 0; n < 4; ++n)
#pragma unroll
            for (int j = 0; j < 4; ++j) {
                const float p = exp2f(accS[n][j] - mnew);
                accS[n][j] = p;
                rs += p;
            }
        rs += __shfl_xor(rs, 16);
        rs += __shfl_xor(rs, 32);
        l_i = l_i * corr + rs;

        // Broadcast corr to accO's row layout (rows q = fq*4+j) and rescale
        {
            float cj[4];
#pragma unroll
            for (int j = 0; j < 4; ++j)
                cj[j] = __shfl(corr, (lane & 48) + fq * 4 + j);
#pragma unroll
            for (int n = 0; n < 4; ++n)
#pragma unroll
                for (int j = 0; j < 4; ++j) accO[n][j] *= cj[j];
        }

        // Pack P row into per-wave LDS (4 x ds_write_b64), then read A-frags
#pragma unroll
        for (int n = 0; n < 4; ++n) {
            union { _Float16 hh[4]; uint2 u; } pk;
#pragma unroll
            for (int j = 0; j < 4; ++j) pk.hh[j] = (_Float16)accS[n][j];
            *reinterpret_cast<uint2*>(pbase + ((n * 32 + fq * 8) ^ swz)) = pk.u;
        }
        f16x8 pa[2];
#pragma unroll
        for (int c = 0; c < 2; ++c)
            pa[c] = *reinterpret_cast<const f16x8*>(pbase + ((c * 64 + fq * 16) ^ swz));

        // O += P V : acc col d = n*16+fr, row q = fq*4+j
#pragma unroll
        for (int n = 0; n < 4; ++n)
#pragma unroll
            for (int c = 0; c < 2; ++c) {
                const int r  = n * 16 + fr;
                const int cc = c * 4 + fq;
                const f16x8 vf = *reinterpret_cast<const f16x8*>(
                    &Vs[r * 64 + ((cc ^ (r & 7)) << 3)]);
                accO[n] = __builtin_amdgcn_mfma_f32_16x16x32_f16(pa[c], vf, accO[n], 0, 0, 0);
            }
    }

    // Epilogue: broadcast 1/l to accO rows, write ao single fp16
    const float invl = 1.0f / l_i;
    float iv[4];
#pragma unroll
    for (int j = 0; j < 4; ++j)
        iv[j] = __shfl(invl, (lane & 48) + fq * 4 + j);
#pragma unroll
    for (int j = 0; j < 4; ++j) {
        const size_t rowg = (size_t)(b * Sseq + qb * 128 + wid * 16 + fq * 4 + j) * NQc;
#pragma unroll
        for (int n = 0; n < 4; ++n)
            ao16[rowg + h * HDm + n * 16 + fr] = (_Float16)(accO[n][j] * iv[j]);
    }
}

// ---------------------------------------------------------------------------
// Launcher. Workspace (40 MB):
//  0..8 wqT16 | 8..10 wkT16 | 10..12 wvT16 | 12..20 woT16
//  20..28 xh (later ao16) | 28..36 qh | 36..38 kh | 38..40 vT
// ---------------------------------------------------------------------------
extern "C" void kernel_launch(void* const* d_in, const int* in_sizes, int n_in,
                              void* d_out, int out_size, void* d_ws, size_t ws_size,
                              hipStream_t stream)
{
    const float* x    = (const float*)d_in[0];
    const float* wq   = (const float*)d_in[1];
    const float* wk   = (const float*)d_in[2];
    const float* wv   = (const float*)d_in[3];
    const float* wo   = (const float*)d_in[4];
    const float* cosT = (const float*)d_in[5];
    const float* sinT = (const float*)d_in[6];
    const int*   spp  = (const int*)d_in[7];
    float*       out  = (float*)d_out;

    char* w = (char*)d_ws;
    _Float16* wqT16 = (_Float16*)(w);
    _Float16* wkT16 = (_Float16*)(w + (8ull  << 20));
    _Float16* wvT16 = (_Float16*)(w + (10ull << 20));
    _Float16* woT16 = (_Float16*)(w + (12ull << 20));
    _Float16* xh    = (_Float16*)(w + (20ull << 20));
    _Float16* ao16  = (_Float16*)(w + (20ull << 20));  // alias xh (dead post-QKV)
    _Float16* qh    = (_Float16*)(w + (28ull << 20));
    _Float16* kh    = (_Float16*)(w + (36ull << 20));
    _Float16* vT    = (_Float16*)(w + (38ull << 20));

    // Input conversions
    conv_x16<<<2048, 256, 0, stream>>>(x, xh);
    conv_w16t<<<10240, 256, 0, stream>>>(wq, wk, wv, wo, wqT16, wkT16, wvT16, woT16);

    // Fused QKV projection + RoPE + packing (q fp16 pre-scaled, k fp16, vT fp16)
    gemm_qkv2<<<dim3(24, 32), 256, 0, stream>>>(xh, wqT16, wkT16, wvT16,
                                                cosT, sinT, qh, kh, vT);

    // Swapped-QK MFMA flash attention, async-staged (writes ao fp16)
    flash_mfma<<<dim3(Sseq / 128, Hq, Bsz), 512, 0, stream>>>(qh, kh, vT, ao16, spp);

    // Output projection
    gemm_out2<<<dim3(16, 32), 256, 0, stream>>>(ao16, woT16, out);
}